// Round 4
// baseline (490.578 us; speedup 1.0000x reference)
//
#include <hip/hip_runtime.h>

// ---------------------------------------------------------------------------
// GCNConv (PyG) + relu + log_softmax, MI355X.
// R3 lesson: accum at 27% occupancy (782 blocks = 3/CU) was latency-bound on
// scattered h reads (359us, HBM 5%). R4: CPB=64 (1563 buckets), 512-thr accum
// blocks, CHUNK=4096 binning blocks, nontemporal streams. Same algorithm.
// ---------------------------------------------------------------------------

typedef unsigned int u32;

#define CPB 64         // cols per bucket
#define CPB_LOG 6
#define MAXNB 2048
#define CHUNK 4096     // edges per binning block

__global__ void detect_i64_kernel(const u32* __restrict__ ew, int* __restrict__ flag) {
    if (threadIdx.x == 0 && blockIdx.x == 0) {
        int is64 = 1;
        for (int i = 0; i < 256; ++i) {
            if (ew[2 * i + 1] != 0u) { is64 = 0; break; }
        }
        *flag = is64;
    }
}

// h = x @ W   (N x 128) @ (128 x 16) -> (N x 16)
__global__ __launch_bounds__(256) void linear_kernel(const float* __restrict__ x,
                                                     const float* __restrict__ W,
                                                     float* __restrict__ h, int N) {
    __shared__ float Ws[128 * 16];
    __shared__ float Xs[16 * 129];
    int tid = threadIdx.x;
    for (int i = tid; i < 2048; i += 256) Ws[i] = W[i];
    long long rbase = (long long)blockIdx.x * 16;
    for (int i = tid; i < 2048; i += 256) {
        int row = i >> 7, k = i & 127;
        long long grow = rbase + row;
        Xs[row * 129 + k] = (grow < N) ? x[grow * 128 + k] : 0.f;
    }
    __syncthreads();
    int rl = tid >> 4, c = tid & 15;
    float acc = 0.f;
#pragma unroll
    for (int k = 0; k < 128; ++k)
        acc = fmaf(Xs[rl * 129 + k], Ws[k * 16 + c], acc);
    long long row = rbase + rl;
    if (row < N) h[row * 16 + c] = acc;
}

// Per-chunk LDS histogram of coarse buckets -> global bucket counts.
__global__ __launch_bounds__(256) void hist_kernel(const u32* __restrict__ ew,
                                                   const int* __restrict__ flag,
                                                   u32* __restrict__ bcnt, int E, int NB) {
    __shared__ u32 hh[MAXNB];
    int t = threadIdx.x;
    for (int i = t; i < NB; i += 256) hh[i] = 0;
    __syncthreads();
    int i64 = *flag;
    int cb = blockIdx.x * CHUNK;
    int ce = min(cb + CHUNK, E);
    for (int e = cb + t; e < ce; e += 256) {
        u32 cl = i64 ? __builtin_nontemporal_load(&ew[2 * (E + e)])
                     : __builtin_nontemporal_load(&ew[E + e]);
        atomicAdd(&hh[cl >> CPB_LOG], 1u);
    }
    __syncthreads();
    for (int i = t; i < NB; i += 256)
        if (hh[i]) atomicAdd(&bcnt[i], hh[i]);
}

// Single-block exclusive scan of NB (< MAXNB=2048) bucket counts, 2/thread.
__global__ __launch_bounds__(1024) void scan_kernel(const u32* __restrict__ bcnt,
                                                    u32* __restrict__ bstart,
                                                    u32* __restrict__ gcur, int NB) {
    __shared__ u32 sm[1024];
    int t = threadIdx.x;
    u32 v0 = (2 * t < NB)     ? bcnt[2 * t]     : 0u;
    u32 v1 = (2 * t + 1 < NB) ? bcnt[2 * t + 1] : 0u;
    u32 v = v0 + v1;
    sm[t] = v;
    __syncthreads();
    for (int d = 1; d < 1024; d <<= 1) {
        u32 x = (t >= d) ? sm[t - d] : 0u;
        __syncthreads();
        sm[t] += x;
        __syncthreads();
    }
    u32 excl = sm[t] - v;
    if (2 * t < NB)     { bstart[2 * t] = excl;          gcur[2 * t] = excl; }
    if (2 * t + 1 < NB) { bstart[2 * t + 1] = excl + v0; gcur[2 * t + 1] = excl + v0; }
    if (t == 1023) bstart[NB] = sm[1023];
}

// Re-read edges; reserve per-(block,bucket) ranges; scatter packed u32.
__global__ __launch_bounds__(256) void scatter_bin_kernel(const u32* __restrict__ ew,
                                                          const int* __restrict__ flag,
                                                          u32* __restrict__ gcur,
                                                          u32* __restrict__ binned, int E, int NB) {
    __shared__ u32 hist[MAXNB];
    __shared__ u32 base[MAXNB];
    int t = threadIdx.x;
    for (int i = t; i < NB; i += 256) hist[i] = 0;
    __syncthreads();
    int i64 = *flag;
    int cb = blockIdx.x * CHUNK;
    int ce = min(cb + CHUNK, E);
    for (int e = cb + t; e < ce; e += 256) {
        u32 cl = i64 ? __builtin_nontemporal_load(&ew[2 * (E + e)])
                     : __builtin_nontemporal_load(&ew[E + e]);
        atomicAdd(&hist[cl >> CPB_LOG], 1u);
    }
    __syncthreads();
    for (int i = t; i < NB; i += 256) {
        u32 c = hist[i];
        base[i] = c ? atomicAdd(&gcur[i], c) : 0u;
        hist[i] = 0;   // reuse as local cursor
    }
    __syncthreads();
    for (int e = cb + t; e < ce; e += 256) {
        u32 r, cl;
        if (i64) { r = __builtin_nontemporal_load(&ew[2 * e]);
                   cl = __builtin_nontemporal_load(&ew[2 * (E + e)]); }
        else     { r = __builtin_nontemporal_load(&ew[e]);
                   cl = __builtin_nontemporal_load(&ew[E + e]); }
        u32 bk = cl >> CPB_LOG;
        u32 pos = base[bk] + atomicAdd(&hist[bk], 1u);
        binned[pos] = r | ((cl & (CPB - 1)) << 17);   // N < 2^17
    }
}

// Per-bucket degree from binned data, write dis (coalesced, atomic-free global).
__global__ __launch_bounds__(256) void deg_kernel(const u32* __restrict__ binned,
                                                  const u32* __restrict__ bstart,
                                                  float* __restrict__ dis, int N) {
    __shared__ u32 cnt[CPB];
    int b = blockIdx.x, t = threadIdx.x;
    if (t < CPB) cnt[t] = 0;
    __syncthreads();
    u32 s = bstart[b], e = bstart[b + 1];
    for (u32 i = s + t; i < e; i += 256)
        atomicAdd(&cnt[__builtin_nontemporal_load(&binned[i]) >> 17], 1u);
    __syncthreads();
    int col = (b << CPB_LOG) + t;
    if (t < CPB && col < N) dis[col] = rsqrtf((float)cnt[t] + 1.0f);
}

// One block per bucket: LDS tile accumulate + fused self-loop/bias/relu/log_softmax.
__global__ __launch_bounds__(512) void accum_kernel(const u32* __restrict__ binned,
                                                    const u32* __restrict__ bstart,
                                                    const float* __restrict__ dis,
                                                    const float* __restrict__ h,
                                                    const float* __restrict__ bias,
                                                    float* __restrict__ out, int N) {
    __shared__ float tile[CPB * 16];   // 4 KB
    __shared__ float dt[CPB];
    int b = blockIdx.x, t = threadIdx.x;
    int cbase = b << CPB_LOG;
    for (int i = t; i < CPB * 16; i += 512) tile[i] = 0.f;
    if (t < CPB) {
        int col = cbase + t;
        dt[t] = (col < N) ? dis[col] : 0.f;
    }
    __syncthreads();
    u32 s = bstart[b], e = bstart[b + 1];
    int c = t & 15, g = t >> 4;   // 32 groups of 16 lanes
#pragma unroll 2
    for (u32 i = s + g; i < e; i += 32) {
        u32 p = __builtin_nontemporal_load(&binned[i]);
        u32 r = p & 0x1FFFFu;
        u32 cl = p >> 17;
        float nrm = dis[r] * dt[cl];
        float hv = h[(size_t)r * 16 + c];
        atomicAdd(&tile[(cl << 4) + c], nrm * hv);
    }
    __syncthreads();
    for (int cl = g; cl < CPB; cl += 32) {
        int col = cbase + cl;
        if (col >= N) continue;
        float v = tile[(cl << 4) + c] + h[(size_t)col * 16 + c] * dt[cl] * dt[cl] + bias[c];
        v = fmaxf(v, 0.f);
        float m = v;
#pragma unroll
        for (int off = 1; off < 16; off <<= 1) m = fmaxf(m, __shfl_xor(m, off, 16));
        float ex = expf(v - m);
        float ss = ex;
#pragma unroll
        for (int off = 1; off < 16; off <<= 1) ss += __shfl_xor(ss, off, 16);
        out[(size_t)col * 16 + c] = (v - m) - logf(ss);
    }
}

extern "C" void kernel_launch(void* const* d_in, const int* in_sizes, int n_in,
                              void* d_out, int out_size, void* d_ws, size_t ws_size,
                              hipStream_t stream) {
    const float* x  = (const float*)d_in[0];
    const u32*   ew = (const u32*)d_in[1];
    const float* W  = (const float*)d_in[2];
    const float* b  = (const float*)d_in[3];
    float* out = (float*)d_out;

    int N = in_sizes[0] / 128;   // 100000  (must be < 2^17 for packing)
    int E = in_sizes[1] / 2;     // 3200000
    int NB = (N + CPB - 1) >> CPB_LOG;   // 1563

    char* wsb = (char*)d_ws;
    size_t off = 0;
    int* flag    = (int*)(wsb + off);   off += 256;
    u32* bcnt    = (u32*)(wsb + off);   off += MAXNB * 4;
    u32* bstart  = (u32*)(wsb + off);   off += MAXNB * 4 + 4;
    u32* gcur    = (u32*)(wsb + off);   off += MAXNB * 4;
    float* dis   = (float*)(wsb + off); off += (size_t)N * 4;
    float* h     = (float*)(wsb + off); off += (size_t)N * 64;
    u32* binned  = (u32*)(wsb + off);   off += (size_t)E * 4;

    int nchunks = (E + CHUNK - 1) / CHUNK;

    hipMemsetAsync(bcnt, 0, MAXNB * 4, stream);
    detect_i64_kernel<<<1, 64, 0, stream>>>(ew, flag);
    linear_kernel<<<(N + 15) / 16, 256, 0, stream>>>(x, W, h, N);
    hist_kernel<<<nchunks, 256, 0, stream>>>(ew, flag, bcnt, E, NB);
    scan_kernel<<<1, 1024, 0, stream>>>(bcnt, bstart, gcur, NB);
    scatter_bin_kernel<<<nchunks, 256, 0, stream>>>(ew, flag, gcur, binned, E, NB);
    deg_kernel<<<NB, 256, 0, stream>>>(binned, bstart, dis, N);
    accum_kernel<<<NB, 512, 0, stream>>>(binned, bstart, dis, h, b, out, N);
}

// Round 5
// 489.874 us; speedup vs baseline: 1.0014x; 1.0014x over previous
//
#include <hip/hip_runtime.h>
#include <hip/hip_fp16.h>

// ---------------------------------------------------------------------------
// GCNConv (PyG) + relu + log_softmax, MI355X.
// R4 lesson: accum not occupancy-bound (72%, still 310us). Bottleneck is the
// per-edge random 64B h-line + dis gather + fmul + LDS-atomic chain.
// R5: hs[r] = dis[r]*h[r] in fp16 (32B rows; dt[col] folded into finalize).
// Inner loop = packed-edge load -> half load -> LDS atomic add. u64 edge loads.
// ---------------------------------------------------------------------------

typedef unsigned int u32;
typedef unsigned long long u64;

#define CPB 64         // cols per bucket
#define CPB_LOG 6
#define MAXNB 2048
#define CHUNK 4096     // edges per binning block

__global__ void detect_i64_kernel(const u32* __restrict__ ew, int* __restrict__ flag) {
    if (threadIdx.x == 0 && blockIdx.x == 0) {
        int is64 = 1;
        for (int i = 0; i < 256; ++i) {
            if (ew[2 * i + 1] != 0u) { is64 = 0; break; }
        }
        *flag = is64;
    }
}

// h = x @ W   (N x 128) @ (128 x 16) -> (N x 16)
__global__ __launch_bounds__(256) void linear_kernel(const float* __restrict__ x,
                                                     const float* __restrict__ W,
                                                     float* __restrict__ h, int N) {
    __shared__ float Ws[128 * 16];
    __shared__ float Xs[16 * 129];
    int tid = threadIdx.x;
    for (int i = tid; i < 2048; i += 256) Ws[i] = W[i];
    long long rbase = (long long)blockIdx.x * 16;
    for (int i = tid; i < 2048; i += 256) {
        int row = i >> 7, k = i & 127;
        long long grow = rbase + row;
        Xs[row * 129 + k] = (grow < N) ? x[grow * 128 + k] : 0.f;
    }
    __syncthreads();
    int rl = tid >> 4, c = tid & 15;
    float acc = 0.f;
#pragma unroll
    for (int k = 0; k < 128; ++k)
        acc = fmaf(Xs[rl * 129 + k], Ws[k * 16 + c], acc);
    long long row = rbase + rl;
    if (row < N) h[row * 16 + c] = acc;
}

// Per-chunk LDS histogram of coarse buckets -> global bucket counts.
__global__ __launch_bounds__(256) void hist_kernel(const u32* __restrict__ ew,
                                                   const int* __restrict__ flag,
                                                   u32* __restrict__ bcnt, int E, int NB) {
    __shared__ u32 hh[MAXNB];
    int t = threadIdx.x;
    for (int i = t; i < NB; i += 256) hh[i] = 0;
    __syncthreads();
    int i64 = *flag;
    const u64* ew64 = (const u64*)ew;
    int cb = blockIdx.x * CHUNK;
    int ce = min(cb + CHUNK, E);
    for (int e = cb + t; e < ce; e += 256) {
        u32 cl = i64 ? (u32)__builtin_nontemporal_load(&ew64[E + e])
                     : __builtin_nontemporal_load(&ew[E + e]);
        atomicAdd(&hh[cl >> CPB_LOG], 1u);
    }
    __syncthreads();
    for (int i = t; i < NB; i += 256)
        if (hh[i]) atomicAdd(&bcnt[i], hh[i]);
}

// Single-block exclusive scan of NB (< MAXNB=2048) bucket counts, 2/thread.
__global__ __launch_bounds__(1024) void scan_kernel(const u32* __restrict__ bcnt,
                                                    u32* __restrict__ bstart,
                                                    u32* __restrict__ gcur, int NB) {
    __shared__ u32 sm[1024];
    int t = threadIdx.x;
    u32 v0 = (2 * t < NB)     ? bcnt[2 * t]     : 0u;
    u32 v1 = (2 * t + 1 < NB) ? bcnt[2 * t + 1] : 0u;
    u32 v = v0 + v1;
    sm[t] = v;
    __syncthreads();
    for (int d = 1; d < 1024; d <<= 1) {
        u32 x = (t >= d) ? sm[t - d] : 0u;
        __syncthreads();
        sm[t] += x;
        __syncthreads();
    }
    u32 excl = sm[t] - v;
    if (2 * t < NB)     { bstart[2 * t] = excl;          gcur[2 * t] = excl; }
    if (2 * t + 1 < NB) { bstart[2 * t + 1] = excl + v0; gcur[2 * t + 1] = excl + v0; }
    if (t == 1023) bstart[NB] = sm[1023];
}

// Re-read edges; reserve per-(block,bucket) ranges; scatter packed u32.
__global__ __launch_bounds__(256) void scatter_bin_kernel(const u32* __restrict__ ew,
                                                          const int* __restrict__ flag,
                                                          u32* __restrict__ gcur,
                                                          u32* __restrict__ binned, int E, int NB) {
    __shared__ u32 hist[MAXNB];
    __shared__ u32 base[MAXNB];
    int t = threadIdx.x;
    for (int i = t; i < NB; i += 256) hist[i] = 0;
    __syncthreads();
    int i64 = *flag;
    const u64* ew64 = (const u64*)ew;
    int cb = blockIdx.x * CHUNK;
    int ce = min(cb + CHUNK, E);
    for (int e = cb + t; e < ce; e += 256) {
        u32 cl = i64 ? (u32)__builtin_nontemporal_load(&ew64[E + e])
                     : __builtin_nontemporal_load(&ew[E + e]);
        atomicAdd(&hist[cl >> CPB_LOG], 1u);
    }
    __syncthreads();
    for (int i = t; i < NB; i += 256) {
        u32 c = hist[i];
        base[i] = c ? atomicAdd(&gcur[i], c) : 0u;
        hist[i] = 0;   // reuse as local cursor
    }
    __syncthreads();
    for (int e = cb + t; e < ce; e += 256) {
        u32 r, cl;
        if (i64) { r  = (u32)__builtin_nontemporal_load(&ew64[e]);
                   cl = (u32)__builtin_nontemporal_load(&ew64[E + e]); }
        else     { r  = __builtin_nontemporal_load(&ew[e]);
                   cl = __builtin_nontemporal_load(&ew[E + e]); }
        u32 bk = cl >> CPB_LOG;
        u32 pos = base[bk] + atomicAdd(&hist[bk], 1u);
        binned[pos] = r | ((cl & (CPB - 1)) << 17);   // N < 2^17
    }
}

// Per-bucket degree from binned data, write dis (coalesced, atomic-free global).
__global__ __launch_bounds__(256) void deg_kernel(const u32* __restrict__ binned,
                                                  const u32* __restrict__ bstart,
                                                  float* __restrict__ dis, int N) {
    __shared__ u32 cnt[CPB];
    int b = blockIdx.x, t = threadIdx.x;
    if (t < CPB) cnt[t] = 0;
    __syncthreads();
    u32 s = bstart[b], e = bstart[b + 1];
    for (u32 i = s + t; i < e; i += 256)
        atomicAdd(&cnt[__builtin_nontemporal_load(&binned[i]) >> 17], 1u);
    __syncthreads();
    int col = (b << CPB_LOG) + t;
    if (t < CPB && col < N) dis[col] = rsqrtf((float)cnt[t] + 1.0f);
}

// hs[i] = dis[i/16] * h[i], stored fp16 (32 B per row).
__global__ __launch_bounds__(256) void hs_kernel(const float* __restrict__ h,
                                                 const float* __restrict__ dis,
                                                 __half* __restrict__ hs, int M) {
    int i = blockIdx.x * 256 + threadIdx.x;
    if (i >= M) return;
    hs[i] = __float2half(h[i] * dis[i >> 4]);
}

// One block per bucket: LDS tile accumulate (no per-edge scale) + fused
// dt-scale/self-loop/bias/relu/log_softmax.
__global__ __launch_bounds__(512) void accum_kernel(const u32* __restrict__ binned,
                                                    const u32* __restrict__ bstart,
                                                    const float* __restrict__ dis,
                                                    const __half* __restrict__ hs,
                                                    const float* __restrict__ bias,
                                                    float* __restrict__ out, int N) {
    __shared__ float tile[CPB * 16];   // 4 KB
    int b = blockIdx.x, t = threadIdx.x;
    int cbase = b << CPB_LOG;
    for (int i = t; i < CPB * 16; i += 512) tile[i] = 0.f;
    __syncthreads();
    u32 s = bstart[b], e = bstart[b + 1];
    int c = t & 15, g = t >> 4;   // 32 groups of 16 lanes
#pragma unroll 4
    for (u32 i = s + g; i < e; i += 32) {
        u32 p = __builtin_nontemporal_load(&binned[i]);
        u32 r = p & 0x1FFFFu;
        u32 cl = p >> 17;
        float hv = __half2float(hs[(size_t)r * 16 + c]);
        atomicAdd(&tile[(cl << 4) + c], hv);
    }
    __syncthreads();
    for (int cl = g; cl < CPB; cl += 32) {
        int col = cbase + cl;
        if (col >= N) continue;
        float dt = dis[col];
        float self = __half2float(hs[(size_t)col * 16 + c]);
        float v = dt * (tile[(cl << 4) + c] + self) + bias[c];
        v = fmaxf(v, 0.f);
        float m = v;
#pragma unroll
        for (int off = 1; off < 16; off <<= 1) m = fmaxf(m, __shfl_xor(m, off, 16));
        float ex = expf(v - m);
        float ss = ex;
#pragma unroll
        for (int off = 1; off < 16; off <<= 1) ss += __shfl_xor(ss, off, 16);
        out[(size_t)col * 16 + c] = (v - m) - logf(ss);
    }
}

extern "C" void kernel_launch(void* const* d_in, const int* in_sizes, int n_in,
                              void* d_out, int out_size, void* d_ws, size_t ws_size,
                              hipStream_t stream) {
    const float* x  = (const float*)d_in[0];
    const u32*   ew = (const u32*)d_in[1];
    const float* W  = (const float*)d_in[2];
    const float* b  = (const float*)d_in[3];
    float* out = (float*)d_out;

    int N = in_sizes[0] / 128;   // 100000  (must be < 2^17 for packing)
    int E = in_sizes[1] / 2;     // 3200000
    int NB = (N + CPB - 1) >> CPB_LOG;   // 1563

    char* wsb = (char*)d_ws;
    size_t off = 0;
    int* flag    = (int*)(wsb + off);   off += 256;
    u32* bcnt    = (u32*)(wsb + off);   off += MAXNB * 4;
    u32* bstart  = (u32*)(wsb + off);   off += MAXNB * 4 + 4;
    u32* gcur    = (u32*)(wsb + off);   off += MAXNB * 4;
    float* dis   = (float*)(wsb + off); off += (size_t)N * 4;
    float* h     = (float*)(wsb + off); off += (size_t)N * 64;
    __half* hs   = (__half*)(wsb + off); off += (size_t)N * 32;
    u32* binned  = (u32*)(wsb + off);   off += (size_t)E * 4;

    int nchunks = (E + CHUNK - 1) / CHUNK;

    hipMemsetAsync(bcnt, 0, MAXNB * 4, stream);
    detect_i64_kernel<<<1, 64, 0, stream>>>(ew, flag);
    linear_kernel<<<(N + 15) / 16, 256, 0, stream>>>(x, W, h, N);
    hist_kernel<<<nchunks, 256, 0, stream>>>(ew, flag, bcnt, E, NB);
    scan_kernel<<<1, 1024, 0, stream>>>(bcnt, bstart, gcur, NB);
    scatter_bin_kernel<<<nchunks, 256, 0, stream>>>(ew, flag, gcur, binned, E, NB);
    deg_kernel<<<NB, 256, 0, stream>>>(binned, bstart, dis, N);
    hs_kernel<<<(N * 16 + 255) / 256, 256, 0, stream>>>(h, dis, hs, N * 16);
    accum_kernel<<<NB, 512, 0, stream>>>(binned, bstart, dis, hs, b, out, N);
}

// Round 6
// 234.323 us; speedup vs baseline: 2.0936x; 2.0906x over previous
//
#include <hip/hip_runtime.h>
#include <hip/hip_fp16.h>

// ---------------------------------------------------------------------------
// GCNConv (PyG) + relu + log_softmax, MI355X.
// R5 lesson: 51.2M LDS f32 atomics retire ~1 lane/cyc/CU => 300us floor.
// R6: sort edges to exact col order (bucket sort pass2 with 64 LDS cursors,
// 1 atomic/edge), then per-node wave gather with REGISTER accumulation —
// zero atomics in the hot loop. hs = dis*h prescaled fp16 (32B rows).
// ---------------------------------------------------------------------------

typedef unsigned int u32;
typedef unsigned long long u64;

#define CPB 64         // cols per bucket
#define CPB_LOG 6
#define MAXNB 2048
#define CHUNK 8192     // edges per binning block (R4's 4096 was slower)

__global__ void detect_i64_kernel(const u32* __restrict__ ew, int* __restrict__ flag) {
    if (threadIdx.x == 0 && blockIdx.x == 0) {
        int is64 = 1;
        for (int i = 0; i < 256; ++i) {
            if (ew[2 * i + 1] != 0u) { is64 = 0; break; }
        }
        *flag = is64;
    }
}

// h = x @ W   (N x 128) @ (128 x 16) -> (N x 16)
__global__ __launch_bounds__(256) void linear_kernel(const float* __restrict__ x,
                                                     const float* __restrict__ W,
                                                     float* __restrict__ h, int N) {
    __shared__ float Ws[128 * 16];
    __shared__ float Xs[16 * 129];
    int tid = threadIdx.x;
    for (int i = tid; i < 2048; i += 256) Ws[i] = W[i];
    long long rbase = (long long)blockIdx.x * 16;
    for (int i = tid; i < 2048; i += 256) {
        int row = i >> 7, k = i & 127;
        long long grow = rbase + row;
        Xs[row * 129 + k] = (grow < N) ? x[grow * 128 + k] : 0.f;
    }
    __syncthreads();
    int rl = tid >> 4, c = tid & 15;
    float acc = 0.f;
#pragma unroll
    for (int k = 0; k < 128; ++k)
        acc = fmaf(Xs[rl * 129 + k], Ws[k * 16 + c], acc);
    long long row = rbase + rl;
    if (row < N) h[row * 16 + c] = acc;
}

// Per-chunk LDS histogram of coarse buckets -> global bucket counts.
__global__ __launch_bounds__(256) void hist_kernel(const u32* __restrict__ ew,
                                                   const int* __restrict__ flag,
                                                   u32* __restrict__ bcnt, int E, int NB) {
    __shared__ u32 hh[MAXNB];
    int t = threadIdx.x;
    for (int i = t; i < NB; i += 256) hh[i] = 0;
    __syncthreads();
    int i64 = *flag;
    const u64* ew64 = (const u64*)ew;
    int cb = blockIdx.x * CHUNK;
    int ce = min(cb + CHUNK, E);
    for (int e = cb + t; e < ce; e += 256) {
        u32 cl = i64 ? (u32)__builtin_nontemporal_load(&ew64[E + e])
                     : __builtin_nontemporal_load(&ew[E + e]);
        atomicAdd(&hh[cl >> CPB_LOG], 1u);
    }
    __syncthreads();
    for (int i = t; i < NB; i += 256)
        if (hh[i]) atomicAdd(&bcnt[i], hh[i]);
}

// Single-block exclusive scan of NB (< MAXNB=2048) bucket counts, 2/thread.
__global__ __launch_bounds__(1024) void scan_kernel(const u32* __restrict__ bcnt,
                                                    u32* __restrict__ bstart,
                                                    u32* __restrict__ gcur, int NB) {
    __shared__ u32 sm[1024];
    int t = threadIdx.x;
    u32 v0 = (2 * t < NB)     ? bcnt[2 * t]     : 0u;
    u32 v1 = (2 * t + 1 < NB) ? bcnt[2 * t + 1] : 0u;
    u32 v = v0 + v1;
    sm[t] = v;
    __syncthreads();
    for (int d = 1; d < 1024; d <<= 1) {
        u32 x = (t >= d) ? sm[t - d] : 0u;
        __syncthreads();
        sm[t] += x;
        __syncthreads();
    }
    u32 excl = sm[t] - v;
    if (2 * t < NB)     { bstart[2 * t] = excl;          gcur[2 * t] = excl; }
    if (2 * t + 1 < NB) { bstart[2 * t + 1] = excl + v0; gcur[2 * t + 1] = excl + v0; }
    if (t == 1023) bstart[NB] = sm[1023];
}

// Re-read edges; reserve per-(block,bucket) ranges; scatter packed u32.
__global__ __launch_bounds__(256) void scatter_bin_kernel(const u32* __restrict__ ew,
                                                          const int* __restrict__ flag,
                                                          u32* __restrict__ gcur,
                                                          u32* __restrict__ binned, int E, int NB) {
    __shared__ u32 hist[MAXNB];
    __shared__ u32 base[MAXNB];
    int t = threadIdx.x;
    for (int i = t; i < NB; i += 256) hist[i] = 0;
    __syncthreads();
    int i64 = *flag;
    const u64* ew64 = (const u64*)ew;
    int cb = blockIdx.x * CHUNK;
    int ce = min(cb + CHUNK, E);
    for (int e = cb + t; e < ce; e += 256) {
        u32 cl = i64 ? (u32)__builtin_nontemporal_load(&ew64[E + e])
                     : __builtin_nontemporal_load(&ew[E + e]);
        atomicAdd(&hist[cl >> CPB_LOG], 1u);
    }
    __syncthreads();
    for (int i = t; i < NB; i += 256) {
        u32 c = hist[i];
        base[i] = c ? atomicAdd(&gcur[i], c) : 0u;
        hist[i] = 0;   // reuse as local cursor
    }
    __syncthreads();
    for (int e = cb + t; e < ce; e += 256) {
        u32 r, cl;
        if (i64) { r  = (u32)__builtin_nontemporal_load(&ew64[e]);
                   cl = (u32)__builtin_nontemporal_load(&ew64[E + e]); }
        else     { r  = __builtin_nontemporal_load(&ew[e]);
                   cl = __builtin_nontemporal_load(&ew[E + e]); }
        u32 bk = cl >> CPB_LOG;
        u32 pos = base[bk] + atomicAdd(&hist[bk], 1u);
        binned[pos] = r | ((cl & (CPB - 1)) << 17);   // N < 2^17
    }
}

// One block per bucket: count per-col (fuses degree/dis), wave-scan, then
// place rows into exact col order. 1 LDS atomic per edge per pass.
__global__ __launch_bounds__(256) void sort_kernel(const u32* __restrict__ binned,
                                                   const u32* __restrict__ bstart,
                                                   u32* __restrict__ sorted,
                                                   float* __restrict__ dis,
                                                   u32* __restrict__ colstart,
                                                   int N, int E) {
    __shared__ u32 cnt[CPB];
    __shared__ u32 cur[CPB];
    int b = blockIdx.x, t = threadIdx.x;
    if (t < CPB) cnt[t] = 0;
    __syncthreads();
    u32 s = bstart[b], e = bstart[b + 1];
    for (u32 i = s + t; i < e; i += 256)
        atomicAdd(&cnt[binned[i] >> 17], 1u);
    __syncthreads();
    if (t < 64) {   // wave 0: inclusive shfl-scan over the 64 counts
        u32 v = cnt[t];
        u32 inc = v;
#pragma unroll
        for (int off = 1; off < 64; off <<= 1) {
            u32 o = __shfl_up(inc, off, 64);
            if (t >= off) inc += o;
        }
        u32 excl = inc - v;
        cur[t] = excl;
        int col = (b << CPB_LOG) + t;
        if (col < N) {
            colstart[col] = s + excl;
            dis[col] = rsqrtf((float)v + 1.0f);
        }
    }
    if (b == 0 && t == 0) colstart[N] = (u32)E;
    __syncthreads();
    for (u32 i = s + t; i < e; i += 256) {
        u32 p = binned[i];
        u32 pos = atomicAdd(&cur[p >> 17], 1u);
        sorted[s + pos] = p & 0x1FFFFu;
    }
}

// hs[i] = dis[i/16] * h[i], stored fp16 (32 B per row).
__global__ __launch_bounds__(256) void hs_kernel(const float* __restrict__ h,
                                                 const float* __restrict__ dis,
                                                 __half* __restrict__ hs, int M) {
    int i = blockIdx.x * 256 + threadIdx.x;
    if (i >= M) return;
    hs[i] = __float2half(h[i] * dis[i >> 4]);
}

// One wave per node: contiguous sorted edge rows, register accumulation,
// fused dt-scale/self-loop/bias/relu/log_softmax. No atomics.
__global__ __launch_bounds__(512) void gather_kernel(const u32* __restrict__ sorted,
                                                     const u32* __restrict__ colstart,
                                                     const float* __restrict__ dis,
                                                     const __half* __restrict__ hs,
                                                     const float* __restrict__ bias,
                                                     float* __restrict__ out, int N) {
    int node = blockIdx.x * 8 + (threadIdx.x >> 6);
    if (node >= N) return;
    int lane = threadIdx.x & 63;
    int c = lane & 15, j = lane >> 4;
    u32 s = colstart[node], e = colstart[node + 1];
    float acc = 0.f;
    u32 i = s + j;
    // 16 edges (4 per group) in flight per iteration
    for (; i + 12 < e; i += 16) {
        u32 r0 = __builtin_nontemporal_load(&sorted[i]);
        u32 r1 = __builtin_nontemporal_load(&sorted[i + 4]);
        u32 r2 = __builtin_nontemporal_load(&sorted[i + 8]);
        u32 r3 = __builtin_nontemporal_load(&sorted[i + 12]);
        float v0 = __half2float(hs[(size_t)r0 * 16 + c]);
        float v1 = __half2float(hs[(size_t)r1 * 16 + c]);
        float v2 = __half2float(hs[(size_t)r2 * 16 + c]);
        float v3 = __half2float(hs[(size_t)r3 * 16 + c]);
        acc += (v0 + v1) + (v2 + v3);
    }
    for (; i < e; i += 4)
        acc += __half2float(hs[(size_t)__builtin_nontemporal_load(&sorted[i]) * 16 + c]);
    // reduce the 4 edge-slot groups
    acc += __shfl_xor(acc, 16, 64);
    acc += __shfl_xor(acc, 32, 64);
    float dt = dis[node];
    float v = dt * (acc + __half2float(hs[(size_t)node * 16 + c])) + bias[c];
    v = fmaxf(v, 0.f);
    float m = v;
#pragma unroll
    for (int off = 1; off < 16; off <<= 1) m = fmaxf(m, __shfl_xor(m, off, 16));
    float ex = expf(v - m);
    float ss = ex;
#pragma unroll
    for (int off = 1; off < 16; off <<= 1) ss += __shfl_xor(ss, off, 16);
    if (j == 0) out[(size_t)node * 16 + c] = (v - m) - logf(ss);
}

extern "C" void kernel_launch(void* const* d_in, const int* in_sizes, int n_in,
                              void* d_out, int out_size, void* d_ws, size_t ws_size,
                              hipStream_t stream) {
    const float* x  = (const float*)d_in[0];
    const u32*   ew = (const u32*)d_in[1];
    const float* W  = (const float*)d_in[2];
    const float* b  = (const float*)d_in[3];
    float* out = (float*)d_out;

    int N = in_sizes[0] / 128;   // 100000  (must be < 2^17 for packing)
    int E = in_sizes[1] / 2;     // 3200000
    int NB = (N + CPB - 1) >> CPB_LOG;   // 1563

    char* wsb = (char*)d_ws;
    size_t off = 0;
    int* flag     = (int*)(wsb + off);   off += 256;
    u32* bcnt     = (u32*)(wsb + off);   off += MAXNB * 4;
    u32* bstart   = (u32*)(wsb + off);   off += MAXNB * 4 + 4;
    u32* gcur     = (u32*)(wsb + off);   off += MAXNB * 4;
    float* dis    = (float*)(wsb + off); off += (size_t)N * 4;
    u32* colstart = (u32*)(wsb + off);   off += (size_t)(N + 1) * 4;
    float* h      = (float*)(wsb + off); off += (size_t)N * 64;
    __half* hs    = (__half*)(wsb + off); off += (size_t)N * 32;
    u32* binned   = (u32*)(wsb + off);   off += (size_t)E * 4;
    u32* sorted   = (u32*)(wsb + off);   off += (size_t)E * 4;

    int nchunks = (E + CHUNK - 1) / CHUNK;

    hipMemsetAsync(bcnt, 0, MAXNB * 4, stream);
    detect_i64_kernel<<<1, 64, 0, stream>>>(ew, flag);
    linear_kernel<<<(N + 15) / 16, 256, 0, stream>>>(x, W, h, N);
    hist_kernel<<<nchunks, 256, 0, stream>>>(ew, flag, bcnt, E, NB);
    scan_kernel<<<1, 1024, 0, stream>>>(bcnt, bstart, gcur, NB);
    scatter_bin_kernel<<<nchunks, 256, 0, stream>>>(ew, flag, gcur, binned, E, NB);
    sort_kernel<<<NB, 256, 0, stream>>>(binned, bstart, sorted, dis, colstart, N, E);
    hs_kernel<<<(N * 16 + 255) / 256, 256, 0, stream>>>(h, dis, hs, N * 16);
    gather_kernel<<<(N + 7) / 8, 512, 0, stream>>>(sorted, colstart, dis, hs, b, out, N);
}

// Round 7
// 202.737 us; speedup vs baseline: 2.4198x; 1.1558x over previous
//
#include <hip/hip_runtime.h>
#include <hip/hip_fp16.h>

// ---------------------------------------------------------------------------
// GCNConv (PyG) + relu + log_softmax, MI355X.
// R6 lesson: single-pass 1563-way scatter => per-block windows of ~21B =>
// 90MB writes for a 12.8MB buffer (7x amplification), 95us.
// R7: two radix passes. Pass1: col>>11 (49 buckets, ~670B windows/block).
// Pass2: refine to col>>6 (32 subbuckets/coarse, ~1KB windows/block).
// Then exact col sort + register-accum gather (R6 structure) unchanged.
// ---------------------------------------------------------------------------

typedef unsigned int u32;
typedef unsigned long long u64;

#define MAXNB 2048
#define CHUNK 8192
#define CPB_LOG 6          // final bucket = 64 cols
#define C1_LOG 11          // coarse bucket = 2048 cols
#define SUBS 32            // fine buckets per coarse = 2^(C1_LOG-CPB_LOG)

__global__ void detect_i64_kernel(const u32* __restrict__ ew, int* __restrict__ flag) {
    if (threadIdx.x == 0 && blockIdx.x == 0) {
        int is64 = 1;
        for (int i = 0; i < 256; ++i) {
            if (ew[2 * i + 1] != 0u) { is64 = 0; break; }
        }
        *flag = is64;
    }
}

// h = x @ W   (N x 128) @ (128 x 16) -> (N x 16)
__global__ __launch_bounds__(256) void linear_kernel(const float* __restrict__ x,
                                                     const float* __restrict__ W,
                                                     float* __restrict__ h, int N) {
    __shared__ float Ws[128 * 16];
    __shared__ float Xs[16 * 129];
    int tid = threadIdx.x;
    for (int i = tid; i < 2048; i += 256) Ws[i] = W[i];
    long long rbase = (long long)blockIdx.x * 16;
    for (int i = tid; i < 2048; i += 256) {
        int row = i >> 7, k = i & 127;
        long long grow = rbase + row;
        Xs[row * 129 + k] = (grow < N) ? x[grow * 128 + k] : 0.f;
    }
    __syncthreads();
    int rl = tid >> 4, c = tid & 15;
    float acc = 0.f;
#pragma unroll
    for (int k = 0; k < 128; ++k)
        acc = fmaf(Xs[rl * 129 + k], Ws[k * 16 + c], acc);
    long long row = rbase + rl;
    if (row < N) h[row * 16 + c] = acc;
}

// Fine histogram: fcnt[col>>6] over all edges.
__global__ __launch_bounds__(512) void histf_kernel(const u32* __restrict__ ew,
                                                    const int* __restrict__ flag,
                                                    u32* __restrict__ fcnt, int E, int NB) {
    __shared__ u32 hh[MAXNB];
    int t = threadIdx.x;
    for (int i = t; i < NB; i += 512) hh[i] = 0;
    __syncthreads();
    int i64 = *flag;
    const u64* ew64 = (const u64*)ew;
    int cb = blockIdx.x * CHUNK;
    int ce = min(cb + CHUNK, E);
    for (int e = cb + t; e < ce; e += 512) {
        u32 cl = i64 ? (u32)__builtin_nontemporal_load(&ew64[E + e])
                     : __builtin_nontemporal_load(&ew[E + e]);
        atomicAdd(&hh[cl >> CPB_LOG], 1u);
    }
    __syncthreads();
    for (int i = t; i < NB; i += 512)
        if (hh[i]) atomicAdd(&fcnt[i], hh[i]);
}

// Exclusive scan of NB fine counts -> fstart (immutable) + gcur2 (cursors),
// plus coarse bases gcur1/cb1 derived at 32-bucket boundaries.
__global__ __launch_bounds__(1024) void scan_kernel(const u32* __restrict__ fcnt,
                                                    u32* __restrict__ fstart,
                                                    u32* __restrict__ gcur2,
                                                    u32* __restrict__ gcur1,
                                                    u32* __restrict__ cb1,
                                                    int NB, int NB1, int E) {
    __shared__ u32 sm[1024];
    int t = threadIdx.x;
    u32 v0 = (2 * t < NB)     ? fcnt[2 * t]     : 0u;
    u32 v1 = (2 * t + 1 < NB) ? fcnt[2 * t + 1] : 0u;
    u32 v = v0 + v1;
    sm[t] = v;
    __syncthreads();
    for (int d = 1; d < 1024; d <<= 1) {
        u32 x = (t >= d) ? sm[t - d] : 0u;
        __syncthreads();
        sm[t] += x;
        __syncthreads();
    }
    u32 excl = sm[t] - v;
    if (2 * t < NB)     { fstart[2 * t] = excl;          gcur2[2 * t] = excl; }
    if (2 * t + 1 < NB) { fstart[2 * t + 1] = excl + v0; gcur2[2 * t + 1] = excl + v0; }
    if (t == 1023) fstart[NB] = sm[1023];
    __threadfence_block();
    __syncthreads();
    if (t < NB1) {
        u32 s = fstart[SUBS * t];   // SUBS*t < NB always (last coarse partial)
        gcur1[t] = s;
        cb1[t] = s;
    }
    if (t == NB1) cb1[t] = (u32)E;
}

// Pass 1: scatter by coarse bucket (col>>11). Packed p = r | (col&2047)<<17.
__global__ __launch_bounds__(512) void pass1_kernel(const u32* __restrict__ ew,
                                                    const int* __restrict__ flag,
                                                    u32* __restrict__ gcur1,
                                                    u32* __restrict__ binned1, int E, int NB1) {
    __shared__ u32 hist[64];
    __shared__ u32 base[64];
    int t = threadIdx.x;
    if (t < NB1) hist[t] = 0;
    __syncthreads();
    int i64 = *flag;
    const u64* ew64 = (const u64*)ew;
    int cb = blockIdx.x * CHUNK;
    int ce = min(cb + CHUNK, E);
    for (int e = cb + t; e < ce; e += 512) {
        u32 cl = i64 ? (u32)__builtin_nontemporal_load(&ew64[E + e])
                     : __builtin_nontemporal_load(&ew[E + e]);
        atomicAdd(&hist[cl >> C1_LOG], 1u);
    }
    __syncthreads();
    if (t < NB1) {
        u32 n = hist[t];
        base[t] = n ? atomicAdd(&gcur1[t], n) : 0u;
        hist[t] = 0;
    }
    __syncthreads();
    for (int e = cb + t; e < ce; e += 512) {
        u32 r, cl;
        if (i64) { r  = (u32)__builtin_nontemporal_load(&ew64[e]);
                   cl = (u32)__builtin_nontemporal_load(&ew64[E + e]); }
        else     { r  = __builtin_nontemporal_load(&ew[e]);
                   cl = __builtin_nontemporal_load(&ew[E + e]); }
        u32 c = cl >> C1_LOG;
        u32 pos = base[c] + atomicAdd(&hist[c], 1u);
        binned1[pos] = r | ((cl & ((1u << C1_LOG) - 1)) << 17);
    }
}

// Pass 2: refine coarse regions to 64-col buckets. Coarse id of element i
// found by binary search over cb1[0..NB1]. Output keeps r + low 6 col bits.
__global__ __launch_bounds__(512) void pass2_kernel(const u32* __restrict__ binned1,
                                                    const u32* __restrict__ cb1,
                                                    u32* __restrict__ gcur2,
                                                    u32* __restrict__ binned2,
                                                    int E, int NB, int NB1) {
    __shared__ u32 hist[MAXNB];
    __shared__ u32 base[MAXNB];
    __shared__ u32 cbs[64];
    int t = threadIdx.x;
    for (int i = t; i < NB; i += 512) hist[i] = 0;
    if (t <= NB1) cbs[t] = cb1[t];
    __syncthreads();
    int lo = blockIdx.x * CHUNK;
    int hi = min(lo + CHUNK, E);
    for (int i = lo + t; i < hi; i += 512) {
        u32 p = __builtin_nontemporal_load(&binned1[i]);
        int a = 0, b = NB1 - 1;               // find c: cbs[c] <= i < cbs[c+1]
        while (a < b) { int m = (a + b + 1) >> 1; if (cbs[m] <= (u32)i) a = m; else b = m - 1; }
        u32 f = (u32)a * SUBS + ((p >> 17) >> CPB_LOG);
        atomicAdd(&hist[f], 1u);
    }
    __syncthreads();
    for (int i = t; i < NB; i += 512) {
        u32 n = hist[i];
        base[i] = n ? atomicAdd(&gcur2[i], n) : 0u;
        hist[i] = 0;
    }
    __syncthreads();
    for (int i = lo + t; i < hi; i += 512) {
        u32 p = __builtin_nontemporal_load(&binned1[i]);
        int a = 0, b = NB1 - 1;
        while (a < b) { int m = (a + b + 1) >> 1; if (cbs[m] <= (u32)i) a = m; else b = m - 1; }
        u32 f = (u32)a * SUBS + ((p >> 17) >> CPB_LOG);
        u32 pos = base[f] + atomicAdd(&hist[f], 1u);
        binned2[pos] = p & 0x7FFFFFu;          // r (17b) | col&63 (bits 17..22)
    }
}

// One block per 64-col bucket: exact col order + dis + colstart.
__global__ __launch_bounds__(256) void sort_kernel(const u32* __restrict__ binned2,
                                                   const u32* __restrict__ fstart,
                                                   u32* __restrict__ sorted,
                                                   float* __restrict__ dis,
                                                   u32* __restrict__ colstart,
                                                   int N, int E) {
    __shared__ u32 cnt[64];
    __shared__ u32 cur[64];
    int b = blockIdx.x, t = threadIdx.x;
    if (t < 64) cnt[t] = 0;
    __syncthreads();
    u32 s = fstart[b], e = fstart[b + 1];
    for (u32 i = s + t; i < e; i += 256)
        atomicAdd(&cnt[binned2[i] >> 17], 1u);
    __syncthreads();
    if (t < 64) {
        u32 v = cnt[t];
        u32 inc = v;
#pragma unroll
        for (int off = 1; off < 64; off <<= 1) {
            u32 o = __shfl_up(inc, off, 64);
            if (t >= off) inc += o;
        }
        u32 excl = inc - v;
        cur[t] = excl;
        int col = (b << CPB_LOG) + t;
        if (col < N) {
            colstart[col] = s + excl;
            dis[col] = rsqrtf((float)v + 1.0f);
        }
    }
    if (b == 0 && t == 0) colstart[N] = (u32)E;
    __syncthreads();
    for (u32 i = s + t; i < e; i += 256) {
        u32 p = binned2[i];
        u32 pos = atomicAdd(&cur[p >> 17], 1u);
        sorted[s + pos] = p & 0x1FFFFu;
    }
}

// hs[i] = dis[i/16] * h[i], stored fp16 (32 B per row).
__global__ __launch_bounds__(256) void hs_kernel(const float* __restrict__ h,
                                                 const float* __restrict__ dis,
                                                 __half* __restrict__ hs, int M) {
    int i = blockIdx.x * 256 + threadIdx.x;
    if (i >= M) return;
    hs[i] = __float2half(h[i] * dis[i >> 4]);
}

// One wave per node: contiguous sorted edge rows, register accumulation,
// fused dt-scale/self-loop/bias/relu/log_softmax. No atomics.
__global__ __launch_bounds__(512) void gather_kernel(const u32* __restrict__ sorted,
                                                     const u32* __restrict__ colstart,
                                                     const float* __restrict__ dis,
                                                     const __half* __restrict__ hs,
                                                     const float* __restrict__ bias,
                                                     float* __restrict__ out, int N) {
    int node = blockIdx.x * 8 + (threadIdx.x >> 6);
    if (node >= N) return;
    int lane = threadIdx.x & 63;
    int c = lane & 15, j = lane >> 4;
    u32 s = colstart[node], e = colstart[node + 1];
    float acc = 0.f;
    u32 i = s + j;
    for (; i + 12 < e; i += 16) {
        u32 r0 = __builtin_nontemporal_load(&sorted[i]);
        u32 r1 = __builtin_nontemporal_load(&sorted[i + 4]);
        u32 r2 = __builtin_nontemporal_load(&sorted[i + 8]);
        u32 r3 = __builtin_nontemporal_load(&sorted[i + 12]);
        float v0 = __half2float(hs[(size_t)r0 * 16 + c]);
        float v1 = __half2float(hs[(size_t)r1 * 16 + c]);
        float v2 = __half2float(hs[(size_t)r2 * 16 + c]);
        float v3 = __half2float(hs[(size_t)r3 * 16 + c]);
        acc += (v0 + v1) + (v2 + v3);
    }
    for (; i < e; i += 4)
        acc += __half2float(hs[(size_t)__builtin_nontemporal_load(&sorted[i]) * 16 + c]);
    acc += __shfl_xor(acc, 16, 64);
    acc += __shfl_xor(acc, 32, 64);
    float dt = dis[node];
    float v = dt * (acc + __half2float(hs[(size_t)node * 16 + c])) + bias[c];
    v = fmaxf(v, 0.f);
    float m = v;
#pragma unroll
    for (int off = 1; off < 16; off <<= 1) m = fmaxf(m, __shfl_xor(m, off, 16));
    float ex = expf(v - m);
    float ss = ex;
#pragma unroll
    for (int off = 1; off < 16; off <<= 1) ss += __shfl_xor(ss, off, 16);
    if (j == 0) out[(size_t)node * 16 + c] = (v - m) - logf(ss);
}

extern "C" void kernel_launch(void* const* d_in, const int* in_sizes, int n_in,
                              void* d_out, int out_size, void* d_ws, size_t ws_size,
                              hipStream_t stream) {
    const float* x  = (const float*)d_in[0];
    const u32*   ew = (const u32*)d_in[1];
    const float* W  = (const float*)d_in[2];
    const float* b  = (const float*)d_in[3];
    float* out = (float*)d_out;

    int N = in_sizes[0] / 128;   // 100000 (must be < 2^17 for packing)
    int E = in_sizes[1] / 2;     // 3200000
    int NB  = (N + 63) >> CPB_LOG;      // 1563 fine buckets
    int NB1 = (N + 2047) >> C1_LOG;     // 49 coarse buckets

    char* wsb = (char*)d_ws;
    size_t off = 0;
    int* flag     = (int*)(wsb + off);   off += 256;
    u32* fcnt     = (u32*)(wsb + off);   off += MAXNB * 4;
    u32* fstart   = (u32*)(wsb + off);   off += (MAXNB + 1) * 4;
    u32* gcur2    = (u32*)(wsb + off);   off += MAXNB * 4;
    u32* gcur1    = (u32*)(wsb + off);   off += 256;
    u32* cb1      = (u32*)(wsb + off);   off += 256;
    float* dis    = (float*)(wsb + off); off += (size_t)N * 4;
    u32* colstart = (u32*)(wsb + off);   off += (size_t)(N + 1) * 4;
    float* h      = (float*)(wsb + off); off += (size_t)N * 64;
    __half* hs    = (__half*)(wsb + off); off += (size_t)N * 32;
    u32* binned1  = (u32*)(wsb + off);   off += (size_t)E * 4;   // reused as sorted
    u32* binned2  = (u32*)(wsb + off);   off += (size_t)E * 4;
    u32* sorted   = binned1;   // binned1 dead after pass2

    int nchunks = (E + CHUNK - 1) / CHUNK;

    hipMemsetAsync(fcnt, 0, MAXNB * 4, stream);
    detect_i64_kernel<<<1, 64, 0, stream>>>(ew, flag);
    linear_kernel<<<(N + 15) / 16, 256, 0, stream>>>(x, W, h, N);
    histf_kernel<<<nchunks, 512, 0, stream>>>(ew, flag, fcnt, E, NB);
    scan_kernel<<<1, 1024, 0, stream>>>(fcnt, fstart, gcur2, gcur1, cb1, NB, NB1, E);
    pass1_kernel<<<nchunks, 512, 0, stream>>>(ew, flag, gcur1, binned1, E, NB1);
    pass2_kernel<<<nchunks, 512, 0, stream>>>(binned1, cb1, gcur2, binned2, E, NB, NB1);
    sort_kernel<<<NB, 256, 0, stream>>>(binned2, fstart, sorted, dis, colstart, N, E);
    hs_kernel<<<(N * 16 + 255) / 256, 256, 0, stream>>>(h, dis, hs, N * 16);
    gather_kernel<<<(N + 7) / 8, 512, 0, stream>>>(sorted, colstart, dis, hs, b, out, N);
}

// Round 8
// 196.769 us; speedup vs baseline: 2.4932x; 1.0303x over previous
//
#include <hip/hip_runtime.h>
#include <hip/hip_fp16.h>

// ---------------------------------------------------------------------------
// GCNConv (PyG) + relu + log_softmax, MI355X.
// R7 lesson: gather VALU-heavy (46% busy, scalar half loads); binning kernels
// ran 391 blocks on 256 CUs (2-round makespan, half idle).
// R8: half2 gather (32 edges in flight, half the instrs/edge); histf/pass1/
// pass2 at exactly 512 balanced blocks; vectorized hs; aligned workspace.
// ---------------------------------------------------------------------------

typedef unsigned int u32;
typedef unsigned long long u64;

#define MAXNB 2048
#define CPB_LOG 6          // final bucket = 64 cols
#define C1_LOG 11          // coarse bucket = 2048 cols
#define SUBS 32            // fine buckets per coarse
#define GRID_BIN 512       // balanced grid for streaming/binning kernels

__global__ void detect_i64_kernel(const u32* __restrict__ ew, int* __restrict__ flag) {
    if (threadIdx.x == 0 && blockIdx.x == 0) {
        int is64 = 1;
        for (int i = 0; i < 256; ++i) {
            if (ew[2 * i + 1] != 0u) { is64 = 0; break; }
        }
        *flag = is64;
    }
}

// h = x @ W   (N x 128) @ (128 x 16) -> (N x 16)
__global__ __launch_bounds__(256) void linear_kernel(const float* __restrict__ x,
                                                     const float* __restrict__ W,
                                                     float* __restrict__ h, int N) {
    __shared__ float Ws[128 * 16];
    __shared__ float Xs[16 * 129];
    int tid = threadIdx.x;
    for (int i = tid; i < 2048; i += 256) Ws[i] = W[i];
    long long rbase = (long long)blockIdx.x * 16;
    for (int i = tid; i < 2048; i += 256) {
        int row = i >> 7, k = i & 127;
        long long grow = rbase + row;
        Xs[row * 129 + k] = (grow < N) ? x[grow * 128 + k] : 0.f;
    }
    __syncthreads();
    int rl = tid >> 4, c = tid & 15;
    float acc = 0.f;
#pragma unroll
    for (int k = 0; k < 128; ++k)
        acc = fmaf(Xs[rl * 129 + k], Ws[k * 16 + c], acc);
    long long row = rbase + rl;
    if (row < N) h[row * 16 + c] = acc;
}

// Fine histogram: fcnt[col>>6] over all edges. Balanced grid.
__global__ __launch_bounds__(512) void histf_kernel(const u32* __restrict__ ew,
                                                    const int* __restrict__ flag,
                                                    u32* __restrict__ fcnt, int E, int NB) {
    __shared__ u32 hh[MAXNB];
    int t = threadIdx.x;
    for (int i = t; i < NB; i += 512) hh[i] = 0;
    __syncthreads();
    int i64 = *flag;
    const u64* ew64 = (const u64*)ew;
    int chunk = (E + (int)gridDim.x - 1) / (int)gridDim.x;
    int cb = blockIdx.x * chunk;
    int ce = min(cb + chunk, E);
    for (int e = cb + t; e < ce; e += 512) {
        u32 cl = i64 ? (u32)__builtin_nontemporal_load(&ew64[E + e])
                     : __builtin_nontemporal_load(&ew[E + e]);
        atomicAdd(&hh[cl >> CPB_LOG], 1u);
    }
    __syncthreads();
    for (int i = t; i < NB; i += 512)
        if (hh[i]) atomicAdd(&fcnt[i], hh[i]);
}

// Exclusive scan of NB fine counts -> fstart (+gcur2 cursors), coarse bases.
__global__ __launch_bounds__(1024) void scan_kernel(const u32* __restrict__ fcnt,
                                                    u32* __restrict__ fstart,
                                                    u32* __restrict__ gcur2,
                                                    u32* __restrict__ gcur1,
                                                    u32* __restrict__ cb1,
                                                    int NB, int NB1, int E) {
    __shared__ u32 sm[1024];
    int t = threadIdx.x;
    u32 v0 = (2 * t < NB)     ? fcnt[2 * t]     : 0u;
    u32 v1 = (2 * t + 1 < NB) ? fcnt[2 * t + 1] : 0u;
    u32 v = v0 + v1;
    sm[t] = v;
    __syncthreads();
    for (int d = 1; d < 1024; d <<= 1) {
        u32 x = (t >= d) ? sm[t - d] : 0u;
        __syncthreads();
        sm[t] += x;
        __syncthreads();
    }
    u32 excl = sm[t] - v;
    if (2 * t < NB)     { fstart[2 * t] = excl;          gcur2[2 * t] = excl; }
    if (2 * t + 1 < NB) { fstart[2 * t + 1] = excl + v0; gcur2[2 * t + 1] = excl + v0; }
    if (t == 1023) fstart[NB] = sm[1023];
    __threadfence_block();
    __syncthreads();
    if (t < NB1) {
        u32 s = fstart[SUBS * t];
        gcur1[t] = s;
        cb1[t] = s;
    }
    if (t == NB1) cb1[t] = (u32)E;
}

// Pass 1: scatter by coarse bucket (col>>11). p = r | (col&2047)<<17.
__global__ __launch_bounds__(512) void pass1_kernel(const u32* __restrict__ ew,
                                                    const int* __restrict__ flag,
                                                    u32* __restrict__ gcur1,
                                                    u32* __restrict__ binned1, int E, int NB1) {
    __shared__ u32 hist[64];
    __shared__ u32 base[64];
    int t = threadIdx.x;
    if (t < NB1) hist[t] = 0;
    __syncthreads();
    int i64 = *flag;
    const u64* ew64 = (const u64*)ew;
    int chunk = (E + (int)gridDim.x - 1) / (int)gridDim.x;
    int cb = blockIdx.x * chunk;
    int ce = min(cb + chunk, E);
    for (int e = cb + t; e < ce; e += 512) {
        u32 cl = i64 ? (u32)__builtin_nontemporal_load(&ew64[E + e])
                     : __builtin_nontemporal_load(&ew[E + e]);
        atomicAdd(&hist[cl >> C1_LOG], 1u);
    }
    __syncthreads();
    if (t < NB1) {
        u32 n = hist[t];
        base[t] = n ? atomicAdd(&gcur1[t], n) : 0u;
        hist[t] = 0;
    }
    __syncthreads();
    for (int e = cb + t; e < ce; e += 512) {
        u32 r, cl;
        if (i64) { r  = (u32)__builtin_nontemporal_load(&ew64[e]);
                   cl = (u32)__builtin_nontemporal_load(&ew64[E + e]); }
        else     { r  = __builtin_nontemporal_load(&ew[e]);
                   cl = __builtin_nontemporal_load(&ew[E + e]); }
        u32 c = cl >> C1_LOG;
        u32 pos = base[c] + atomicAdd(&hist[c], 1u);
        binned1[pos] = r | ((cl & ((1u << C1_LOG) - 1)) << 17);
    }
}

// Pass 2: refine coarse regions to 64-col buckets; binary search for coarse id.
__global__ __launch_bounds__(512) void pass2_kernel(const u32* __restrict__ binned1,
                                                    const u32* __restrict__ cb1,
                                                    u32* __restrict__ gcur2,
                                                    u32* __restrict__ binned2,
                                                    int E, int NB, int NB1) {
    __shared__ u32 hist[MAXNB];
    __shared__ u32 base[MAXNB];
    __shared__ u32 cbs[64];
    int t = threadIdx.x;
    for (int i = t; i < NB; i += 512) hist[i] = 0;
    if (t <= NB1) cbs[t] = cb1[t];
    __syncthreads();
    int chunk = (E + (int)gridDim.x - 1) / (int)gridDim.x;
    int lo = blockIdx.x * chunk;
    int hi = min(lo + chunk, E);
    for (int i = lo + t; i < hi; i += 512) {
        u32 p = __builtin_nontemporal_load(&binned1[i]);
        int a = 0, b = NB1 - 1;
        while (a < b) { int m = (a + b + 1) >> 1; if (cbs[m] <= (u32)i) a = m; else b = m - 1; }
        u32 f = (u32)a * SUBS + ((p >> 17) >> CPB_LOG);
        atomicAdd(&hist[f], 1u);
    }
    __syncthreads();
    for (int i = t; i < NB; i += 512) {
        u32 n = hist[i];
        base[i] = n ? atomicAdd(&gcur2[i], n) : 0u;
        hist[i] = 0;
    }
    __syncthreads();
    for (int i = lo + t; i < hi; i += 512) {
        u32 p = __builtin_nontemporal_load(&binned1[i]);
        int a = 0, b = NB1 - 1;
        while (a < b) { int m = (a + b + 1) >> 1; if (cbs[m] <= (u32)i) a = m; else b = m - 1; }
        u32 f = (u32)a * SUBS + ((p >> 17) >> CPB_LOG);
        u32 pos = base[f] + atomicAdd(&hist[f], 1u);
        binned2[pos] = p & 0x7FFFFFu;          // r (17b) | col&63 (bits 17..22)
    }
}

// One block per 64-col bucket: exact col order + dis + colstart.
__global__ __launch_bounds__(256) void sort_kernel(const u32* __restrict__ binned2,
                                                   const u32* __restrict__ fstart,
                                                   u32* __restrict__ sorted,
                                                   float* __restrict__ dis,
                                                   u32* __restrict__ colstart,
                                                   int N, int E) {
    __shared__ u32 cnt[64];
    __shared__ u32 cur[64];
    int b = blockIdx.x, t = threadIdx.x;
    if (t < 64) cnt[t] = 0;
    __syncthreads();
    u32 s = fstart[b], e = fstart[b + 1];
    for (u32 i = s + t; i < e; i += 256)
        atomicAdd(&cnt[binned2[i] >> 17], 1u);
    __syncthreads();
    if (t < 64) {
        u32 v = cnt[t];
        u32 inc = v;
#pragma unroll
        for (int off = 1; off < 64; off <<= 1) {
            u32 o = __shfl_up(inc, off, 64);
            if (t >= off) inc += o;
        }
        u32 excl = inc - v;
        cur[t] = excl;
        int col = (b << CPB_LOG) + t;
        if (col < N) {
            colstart[col] = s + excl;
            dis[col] = rsqrtf((float)v + 1.0f);
        }
    }
    if (b == 0 && t == 0) colstart[N] = (u32)E;
    __syncthreads();
    for (u32 i = s + t; i < e; i += 256) {
        u32 p = binned2[i];
        u32 pos = atomicAdd(&cur[p >> 17], 1u);
        sorted[s + pos] = p & 0x1FFFFu;
    }
}

// hs2[i] = half2( dis[row]*h[2i], dis[row]*h[2i+1] ), row = i>>3.
__global__ __launch_bounds__(256) void hs_kernel(const float* __restrict__ h,
                                                 const float* __restrict__ dis,
                                                 __half2* __restrict__ hs2, int M2) {
    int i = blockIdx.x * 256 + threadIdx.x;
    if (i >= M2) return;
    float d = dis[i >> 3];
    float2 hv = ((const float2*)h)[i];
    hs2[i] = __floats2half2_rn(hv.x * d, hv.y * d);
}

// One wave per node: lane = (j=lane>>3 edge-slot, c2=lane&7 channel-pair).
// 32 edges in flight; register accumulation; fused finalize. No atomics.
__global__ __launch_bounds__(512) void gather_kernel(const u32* __restrict__ sorted,
                                                     const u32* __restrict__ colstart,
                                                     const float* __restrict__ dis,
                                                     const __half2* __restrict__ hs2,
                                                     const float* __restrict__ bias,
                                                     float* __restrict__ out, int N) {
    int node = blockIdx.x * 8 + (threadIdx.x >> 6);
    if (node >= N) return;
    int lane = threadIdx.x & 63;
    int c2 = lane & 7, j = lane >> 3;
    u32 s = colstart[node], e = colstart[node + 1];
    float ax = 0.f, ay = 0.f;
    u32 i = s + j;
    for (; i + 24 < e; i += 32) {
        u32 r0 = __builtin_nontemporal_load(&sorted[i]);
        u32 r1 = __builtin_nontemporal_load(&sorted[i + 8]);
        u32 r2 = __builtin_nontemporal_load(&sorted[i + 16]);
        u32 r3 = __builtin_nontemporal_load(&sorted[i + 24]);
        float2 v0 = __half22float2(hs2[(size_t)r0 * 8 + c2]);
        float2 v1 = __half22float2(hs2[(size_t)r1 * 8 + c2]);
        float2 v2 = __half22float2(hs2[(size_t)r2 * 8 + c2]);
        float2 v3 = __half22float2(hs2[(size_t)r3 * 8 + c2]);
        ax += (v0.x + v1.x) + (v2.x + v3.x);
        ay += (v0.y + v1.y) + (v2.y + v3.y);
    }
    for (; i < e; i += 8) {
        u32 r = __builtin_nontemporal_load(&sorted[i]);
        float2 v = __half22float2(hs2[(size_t)r * 8 + c2]);
        ax += v.x; ay += v.y;
    }
    // reduce the 8 edge-slot groups
#pragma unroll
    for (int off = 8; off < 64; off <<= 1) {
        ax += __shfl_xor(ax, off, 64);
        ay += __shfl_xor(ay, off, 64);
    }
    float dt = dis[node];
    float2 sv = __half22float2(hs2[(size_t)node * 8 + c2]);
    float va = dt * (ax + sv.x) + bias[2 * c2];
    float vb = dt * (ay + sv.y) + bias[2 * c2 + 1];
    va = fmaxf(va, 0.f);
    vb = fmaxf(vb, 0.f);
    float m = fmaxf(va, vb);
#pragma unroll
    for (int off = 1; off < 8; off <<= 1) m = fmaxf(m, __shfl_xor(m, off, 8));
    float ss = expf(va - m) + expf(vb - m);
#pragma unroll
    for (int off = 1; off < 8; off <<= 1) ss += __shfl_xor(ss, off, 8);
    float ls = logf(ss);
    if (j == 0) {
        float2 o = { (va - m) - ls, (vb - m) - ls };
        ((float2*)(out + (size_t)node * 16))[c2] = o;
    }
}

extern "C" void kernel_launch(void* const* d_in, const int* in_sizes, int n_in,
                              void* d_out, int out_size, void* d_ws, size_t ws_size,
                              hipStream_t stream) {
    const float* x  = (const float*)d_in[0];
    const u32*   ew = (const u32*)d_in[1];
    const float* W  = (const float*)d_in[2];
    const float* b  = (const float*)d_in[3];
    float* out = (float*)d_out;

    int N = in_sizes[0] / 128;   // 100000 (must be < 2^17 for packing)
    int E = in_sizes[1] / 2;     // 3200000
    int NB  = (N + 63) >> CPB_LOG;      // 1563 fine buckets
    int NB1 = (N + 2047) >> C1_LOG;     // 49 coarse buckets

    char* wsb = (char*)d_ws;
    size_t off = 0;
    auto alloc = [&](size_t sz) { void* p = wsb + off; off = (off + sz + 15) & ~(size_t)15; return p; };
    int* flag     = (int*)alloc(4);
    u32* fcnt     = (u32*)alloc(MAXNB * 4);
    u32* fstart   = (u32*)alloc((MAXNB + 1) * 4);
    u32* gcur2    = (u32*)alloc(MAXNB * 4);
    u32* gcur1    = (u32*)alloc(256);
    u32* cb1      = (u32*)alloc(256);
    float* dis    = (float*)alloc((size_t)N * 4);
    u32* colstart = (u32*)alloc((size_t)(N + 1) * 4);
    float* h      = (float*)alloc((size_t)N * 64);
    __half2* hs2  = (__half2*)alloc((size_t)N * 32);
    u32* binned1  = (u32*)alloc((size_t)E * 4);   // reused as sorted
    u32* binned2  = (u32*)alloc((size_t)E * 4);
    u32* sorted   = binned1;                      // binned1 dead after pass2

    hipMemsetAsync(fcnt, 0, MAXNB * 4, stream);
    detect_i64_kernel<<<1, 64, 0, stream>>>(ew, flag);
    linear_kernel<<<(N + 15) / 16, 256, 0, stream>>>(x, W, h, N);
    histf_kernel<<<GRID_BIN, 512, 0, stream>>>(ew, flag, fcnt, E, NB);
    scan_kernel<<<1, 1024, 0, stream>>>(fcnt, fstart, gcur2, gcur1, cb1, NB, NB1, E);
    pass1_kernel<<<GRID_BIN, 512, 0, stream>>>(ew, flag, gcur1, binned1, E, NB1);
    pass2_kernel<<<GRID_BIN, 512, 0, stream>>>(binned1, cb1, gcur2, binned2, E, NB, NB1);
    sort_kernel<<<NB, 256, 0, stream>>>(binned2, fstart, sorted, dis, colstart, N, E);
    hs_kernel<<<(N * 8 + 255) / 256, 256, 0, stream>>>(h, dis, hs2, N * 8);
    gather_kernel<<<(N + 7) / 8, 512, 0, stream>>>(sorted, colstart, dis, hs2, b, out, N);
}

// Round 9
// 170.690 us; speedup vs baseline: 2.8741x; 1.1528x over previous
//
#include <hip/hip_runtime.h>
#include <hip/hip_fp16.h>

// ---------------------------------------------------------------------------
// GCNConv (PyG) + relu + log_softmax, MI355X.
// R8 lesson: gather finalize (wave-wide shfl/exp per single node) ~= edge work;
// histf duplicated pass1's col read; pass2 binary-search per element.
// R9: (1) gather = 4 nodes/wave (finalize cost /4); (2) pass1 scatters into
// fixed-CAP coarse regions (no pre-scan; fine hist fused into same pass);
// (3) pass2 blocks are per-region (no search); (4) sort fuses dis+hs2; linear
// stores h in fp16.
// ---------------------------------------------------------------------------

typedef unsigned int u32;
typedef unsigned long long u64;

#define MAXNB 2048
#define CPB_LOG 6          // fine bucket = 64 cols
#define C1_LOG 11          // coarse region = 2048 cols
#define SUBS 32            // fine buckets per coarse region
#define NB1_MAX 64
#define RPB 10             // pass2 blocks per coarse region
#define GRID_BIN 512

// init: detect int64-vs-int32 edge storage + init coarse cursors to c*cap.
__global__ void init_kernel(const u32* __restrict__ ew, int* __restrict__ flag,
                            u32* __restrict__ gcur1, int NB1, int cap) {
    int t = threadIdx.x;
    if (t < NB1) gcur1[t] = (u32)(t * cap);
    if (t == 0) {
        int is64 = 1;
        for (int i = 0; i < 256; ++i) {
            if (ew[2 * i + 1] != 0u) { is64 = 0; break; }
        }
        *flag = is64;
    }
}

// h16 = fp16(x @ W)   (N x 128) @ (128 x 16) -> (N x 16)
__global__ __launch_bounds__(256) void linear_kernel(const float* __restrict__ x,
                                                     const float* __restrict__ W,
                                                     __half* __restrict__ h16, int N) {
    __shared__ float Ws[128 * 16];
    __shared__ float Xs[16 * 129];
    int tid = threadIdx.x;
    for (int i = tid; i < 2048; i += 256) Ws[i] = W[i];
    long long rbase = (long long)blockIdx.x * 16;
    for (int i = tid; i < 2048; i += 256) {
        int row = i >> 7, k = i & 127;
        long long grow = rbase + row;
        Xs[row * 129 + k] = (grow < N) ? x[grow * 128 + k] : 0.f;
    }
    __syncthreads();
    int rl = tid >> 4, c = tid & 15;
    float acc = 0.f;
#pragma unroll
    for (int k = 0; k < 128; ++k)
        acc = fmaf(Xs[rl * 129 + k], Ws[k * 16 + c], acc);
    long long row = rbase + rl;
    if (row < N) h16[row * 16 + c] = __float2half(acc);
}

// Pass 1: one read of cols builds the fine histogram (flushed to fcnt) AND
// reserves coarse space (regions pre-based at c*cap, no pre-scan); second
// read places packed edges into coarse regions.
__global__ __launch_bounds__(512) void pass1_kernel(const u32* __restrict__ ew,
                                                    const int* __restrict__ flag,
                                                    u32* __restrict__ fcnt,
                                                    u32* __restrict__ gcur1,
                                                    u32* __restrict__ binned1,
                                                    int E, int NB, int NB1) {
    __shared__ u32 fh[MAXNB];
    __shared__ u32 ccur[NB1_MAX];
    int t = threadIdx.x;
    for (int i = t; i < NB; i += 512) fh[i] = 0;
    __syncthreads();
    int i64 = *flag;
    const u64* ew64 = (const u64*)ew;
    int chunk = (E + (int)gridDim.x - 1) / (int)gridDim.x;
    int cb = blockIdx.x * chunk;
    int ce = min(cb + chunk, E);
    for (int e = cb + t; e < ce; e += 512) {
        u32 cl = i64 ? (u32)__builtin_nontemporal_load(&ew64[E + e])
                     : __builtin_nontemporal_load(&ew[E + e]);
        atomicAdd(&fh[cl >> CPB_LOG], 1u);
    }
    __syncthreads();
    for (int i = t; i < NB; i += 512)
        if (fh[i]) atomicAdd(&fcnt[i], fh[i]);
    if (t < NB1) {
        u32 n = 0;
        int base = t * SUBS, end = min(base + SUBS, NB);
        for (int k = base; k < end; ++k) n += fh[k];
        ccur[t] = n ? atomicAdd(&gcur1[t], n) : 0u;
    }
    __syncthreads();
    for (int e = cb + t; e < ce; e += 512) {
        u32 r, cl;
        if (i64) { r  = (u32)__builtin_nontemporal_load(&ew64[e]);
                   cl = (u32)__builtin_nontemporal_load(&ew64[E + e]); }
        else     { r  = __builtin_nontemporal_load(&ew[e]);
                   cl = __builtin_nontemporal_load(&ew[E + e]); }
        u32 c = cl >> C1_LOG;
        u32 pos = atomicAdd(&ccur[c], 1u);
        binned1[pos] = r | ((cl & ((1u << C1_LOG) - 1)) << 17);
    }
}

// Exclusive scan of NB fine counts -> fstart (immutable) + gcur2 (cursors).
__global__ __launch_bounds__(1024) void scan_kernel(const u32* __restrict__ fcnt,
                                                    u32* __restrict__ fstart,
                                                    u32* __restrict__ gcur2, int NB) {
    __shared__ u32 sm[1024];
    int t = threadIdx.x;
    u32 v0 = (2 * t < NB)     ? fcnt[2 * t]     : 0u;
    u32 v1 = (2 * t + 1 < NB) ? fcnt[2 * t + 1] : 0u;
    u32 v = v0 + v1;
    sm[t] = v;
    __syncthreads();
    for (int d = 1; d < 1024; d <<= 1) {
        u32 x = (t >= d) ? sm[t - d] : 0u;
        __syncthreads();
        sm[t] += x;
        __syncthreads();
    }
    u32 excl = sm[t] - v;
    if (2 * t < NB)     { fstart[2 * t] = excl;          gcur2[2 * t] = excl; }
    if (2 * t + 1 < NB) { fstart[2 * t + 1] = excl + v0; gcur2[2 * t + 1] = excl + v0; }
    if (t == 1023) fstart[NB] = sm[1023];
}

// Pass 2: per-region refinement (block b -> region b/RPB); 32 LDS counters.
__global__ __launch_bounds__(512) void pass2_kernel(const u32* __restrict__ binned1,
                                                    const u32* __restrict__ gcur1,
                                                    u32* __restrict__ gcur2,
                                                    u32* __restrict__ binned2,
                                                    int cap) {
    __shared__ u32 scur[SUBS];
    int b = blockIdx.x;
    int c = b / RPB, sub = b - c * RPB;
    int t = threadIdx.x;
    int rbeg = c * cap;
    int rend = (int)gcur1[c];
    int len = rend - rbeg;
    int chunk = (len + RPB - 1) / RPB;
    int lo = rbeg + sub * chunk;
    int hi = min(lo + chunk, rend);
    if (t < SUBS) scur[t] = 0;
    __syncthreads();
    for (int i = lo + t; i < hi; i += 512)
        atomicAdd(&scur[(__builtin_nontemporal_load(&binned1[i]) >> 17) >> CPB_LOG], 1u);
    __syncthreads();
    if (t < SUBS) {
        u32 n = scur[t];
        scur[t] = n ? atomicAdd(&gcur2[c * SUBS + t], n) : 0u;
    }
    __syncthreads();
    for (int i = lo + t; i < hi; i += 512) {
        u32 p = __builtin_nontemporal_load(&binned1[i]);
        u32 s = (p >> 17) >> CPB_LOG;
        u32 pos = atomicAdd(&scur[s], 1u);
        binned2[pos] = p & 0x7FFFFFu;          // r (17b) | col&63 (bits 17..22)
    }
}

// One block per 64-col bucket: exact col order + colstart + dis + fused hs2.
__global__ __launch_bounds__(256) void sort_kernel(const u32* __restrict__ binned2,
                                                   const u32* __restrict__ fstart,
                                                   u32* __restrict__ sorted,
                                                   float* __restrict__ dis,
                                                   u32* __restrict__ colstart,
                                                   const __half2* __restrict__ h16,
                                                   __half2* __restrict__ hs2,
                                                   int N, int E) {
    __shared__ u32 cnt[64];
    __shared__ u32 cur[64];
    __shared__ float dsm[64];
    int b = blockIdx.x, t = threadIdx.x;
    if (t < 64) cnt[t] = 0;
    __syncthreads();
    u32 s = fstart[b], e = fstart[b + 1];
    for (u32 i = s + t; i < e; i += 256)
        atomicAdd(&cnt[binned2[i] >> 17], 1u);
    __syncthreads();
    if (t < 64) {
        u32 v = cnt[t];
        u32 inc = v;
#pragma unroll
        for (int off = 1; off < 64; off <<= 1) {
            u32 o = __shfl_up(inc, off, 64);
            if (t >= off) inc += o;
        }
        u32 excl = inc - v;
        cur[t] = excl;
        int col = (b << CPB_LOG) + t;
        if (col < N) {
            colstart[col] = s + excl;
            float dv = rsqrtf((float)v + 1.0f);
            dis[col] = dv;
            dsm[t] = dv;
        }
    }
    if (b == 0 && t == 0) colstart[N] = (u32)E;
    __syncthreads();
    // fused hs2 = dis * h16 for this block's 64 cols (512 half2 elems)
#pragma unroll
    for (int q = 0; q < 2; ++q) {
        int idx = t + 256 * q;
        int lcol = idx >> 3, k = idx & 7;
        int col = (b << CPB_LOG) + lcol;
        if (col < N) {
            float d = dsm[lcol];
            float2 hv = __half22float2(h16[(size_t)col * 8 + k]);
            hs2[(size_t)col * 8 + k] = __floats2half2_rn(hv.x * d, hv.y * d);
        }
    }
    for (u32 i = s + t; i < e; i += 256) {
        u32 p = binned2[i];
        u32 pos = atomicAdd(&cur[p >> 17], 1u);
        sorted[s + pos] = p & 0x1FFFFu;
    }
}

// 4 nodes per wave: 16 lanes/node = (j in {0,1} edge-slots) x (c2 in 0..7
// channel-pairs). Register accumulation, unroll 8 (16 edges in flight/node).
// Finalize shfls/exp serve 4 nodes per wave op.
__global__ __launch_bounds__(512) void gather_kernel(const u32* __restrict__ sorted,
                                                     const u32* __restrict__ colstart,
                                                     const float* __restrict__ dis,
                                                     const __half2* __restrict__ hs2,
                                                     const float* __restrict__ bias,
                                                     float* __restrict__ out, int N) {
    int tid = threadIdx.x;
    int node = blockIdx.x * 32 + (tid >> 4);
    if (node >= N) return;
    int l16 = tid & 15;
    int c2 = l16 & 7, j = l16 >> 3;
    u32 s = colstart[node], e = colstart[node + 1];
    float ax = 0.f, ay = 0.f;
    u32 i = s + j;
    for (; i + 14 < e; i += 16) {
        u32 r0 = __builtin_nontemporal_load(&sorted[i]);
        u32 r1 = __builtin_nontemporal_load(&sorted[i + 2]);
        u32 r2 = __builtin_nontemporal_load(&sorted[i + 4]);
        u32 r3 = __builtin_nontemporal_load(&sorted[i + 6]);
        u32 r4 = __builtin_nontemporal_load(&sorted[i + 8]);
        u32 r5 = __builtin_nontemporal_load(&sorted[i + 10]);
        u32 r6 = __builtin_nontemporal_load(&sorted[i + 12]);
        u32 r7 = __builtin_nontemporal_load(&sorted[i + 14]);
        float2 v0 = __half22float2(hs2[(size_t)r0 * 8 + c2]);
        float2 v1 = __half22float2(hs2[(size_t)r1 * 8 + c2]);
        float2 v2 = __half22float2(hs2[(size_t)r2 * 8 + c2]);
        float2 v3 = __half22float2(hs2[(size_t)r3 * 8 + c2]);
        float2 v4 = __half22float2(hs2[(size_t)r4 * 8 + c2]);
        float2 v5 = __half22float2(hs2[(size_t)r5 * 8 + c2]);
        float2 v6 = __half22float2(hs2[(size_t)r6 * 8 + c2]);
        float2 v7 = __half22float2(hs2[(size_t)r7 * 8 + c2]);
        ax += ((v0.x + v1.x) + (v2.x + v3.x)) + ((v4.x + v5.x) + (v6.x + v7.x));
        ay += ((v0.y + v1.y) + (v2.y + v3.y)) + ((v4.y + v5.y) + (v6.y + v7.y));
    }
    for (; i < e; i += 2) {
        u32 r = __builtin_nontemporal_load(&sorted[i]);
        float2 v = __half22float2(hs2[(size_t)r * 8 + c2]);
        ax += v.x; ay += v.y;
    }
    // j-slot reduce (within the 16-lane node group)
    ax += __shfl_xor(ax, 8, 64);
    ay += __shfl_xor(ay, 8, 64);
    float dt = dis[node];
    float2 sv = __half22float2(hs2[(size_t)node * 8 + c2]);
    float2 bb = ((const float2*)bias)[c2];
    float va = fmaxf(dt * (ax + sv.x) + bb.x, 0.f);
    float vb = fmaxf(dt * (ay + sv.y) + bb.y, 0.f);
    // log_softmax over 16 channels = 8 c2 lanes
    float m = fmaxf(va, vb);
#pragma unroll
    for (int off = 1; off < 8; off <<= 1) m = fmaxf(m, __shfl_xor(m, off, 64));
    float ss = expf(va - m) + expf(vb - m);
#pragma unroll
    for (int off = 1; off < 8; off <<= 1) ss += __shfl_xor(ss, off, 64);
    float ls = logf(ss);
    if (j == 0) {
        float2 o = { (va - m) - ls, (vb - m) - ls };
        ((float2*)(out + (size_t)node * 16))[c2] = o;
    }
}

extern "C" void kernel_launch(void* const* d_in, const int* in_sizes, int n_in,
                              void* d_out, int out_size, void* d_ws, size_t ws_size,
                              hipStream_t stream) {
    const float* x  = (const float*)d_in[0];
    const u32*   ew = (const u32*)d_in[1];
    const float* W  = (const float*)d_in[2];
    const float* b  = (const float*)d_in[3];
    float* out = (float*)d_out;

    int N = in_sizes[0] / 128;   // 100000 (must be < 2^17 for packing)
    int E = in_sizes[1] / 2;     // 3200000
    int NB  = (N + 63) >> CPB_LOG;              // 1563 fine buckets
    int NB1 = (N + ((1 << C1_LOG) - 1)) >> C1_LOG;   // 49 coarse regions
    int cap = E / NB1 + 8192;                   // slack region capacity

    char* wsb = (char*)d_ws;
    size_t off = 0;
    auto alloc = [&](size_t sz) { void* p = wsb + off; off = (off + sz + 15) & ~(size_t)15; return p; };
    int* flag     = (int*)alloc(4);
    u32* fcnt     = (u32*)alloc(MAXNB * 4);
    u32* fstart   = (u32*)alloc((MAXNB + 1) * 4);
    u32* gcur2    = (u32*)alloc(MAXNB * 4);
    u32* gcur1    = (u32*)alloc(NB1_MAX * 4);
    float* dis    = (float*)alloc((size_t)N * 4);
    u32* colstart = (u32*)alloc((size_t)(N + 1) * 4);
    __half* h16   = (__half*)alloc((size_t)N * 32);
    __half2* hs2  = (__half2*)alloc((size_t)N * 32);
    u32* binned1  = (u32*)alloc((size_t)NB1 * cap * 4);  // slack regions; reused as sorted
    u32* binned2  = (u32*)alloc((size_t)E * 4);
    u32* sorted   = binned1;   // binned1 dead after pass2

    hipMemsetAsync(fcnt, 0, MAXNB * 4, stream);
    init_kernel<<<1, 64, 0, stream>>>(ew, flag, gcur1, NB1, cap);
    linear_kernel<<<(N + 15) / 16, 256, 0, stream>>>(x, W, h16, N);
    pass1_kernel<<<GRID_BIN, 512, 0, stream>>>(ew, flag, fcnt, gcur1, binned1, E, NB, NB1);
    scan_kernel<<<1, 1024, 0, stream>>>(fcnt, fstart, gcur2, NB);
    pass2_kernel<<<NB1 * RPB, 512, 0, stream>>>(binned1, gcur1, gcur2, binned2, cap);
    sort_kernel<<<NB, 256, 0, stream>>>(binned2, fstart, sorted, dis, colstart,
                                        (const __half2*)h16, hs2, N, E);
    gather_kernel<<<(N + 31) / 32, 512, 0, stream>>>(sorted, colstart, dis, hs2, b, out, N);
}

// Round 10
// 139.974 us; speedup vs baseline: 3.5048x; 1.2194x over previous
//
#include <hip/hip_runtime.h>
#include <hip/hip_fp16.h>

// ---------------------------------------------------------------------------
// GCNConv (PyG) + relu + log_softmax, MI355X.
// R9 lesson: sort->sorted->gather round-trip (25us kernel + 12.8MB write +
// 12.8MB read) exists only to make col lists contiguous; gather was also
// half-busy reading that stream.
// R10: pass2 produces per-col degrees cnt[N] (2048-counter LDS hist, same
// atomic count); gather fuses the col-sort in LDS (place by scanned offsets,
// 1 LDS atomic/edge) + work-stealing col assignment + register accumulation
// + fused finalize. sort_kernel and the sorted buffer are gone.
// ---------------------------------------------------------------------------

typedef unsigned int u32;
typedef unsigned long long u64;

#define MAXNB 2048
#define CPB_LOG 6          // fine bucket = 64 cols
#define C1_LOG 11          // coarse region = 2048 cols
#define SUBS 32            // fine buckets per coarse region
#define NB1_MAX 64
#define RPB 10             // pass2 blocks per coarse region
#define GRID_BIN 512
#define TCAP 3072          // fgather LDS tile capacity (mean 2048, sigma~45)

// init: detect int64-vs-int32 edge storage + init coarse cursors to c*cap.
__global__ void init_kernel(const u32* __restrict__ ew, int* __restrict__ flag,
                            u32* __restrict__ gcur1, int NB1, int cap) {
    int t = threadIdx.x;
    if (t < NB1) gcur1[t] = (u32)(t * cap);
    if (t == 0) {
        int is64 = 1;
        for (int i = 0; i < 256; ++i) {
            if (ew[2 * i + 1] != 0u) { is64 = 0; break; }
        }
        *flag = is64;
    }
}

// h16 = fp16(x @ W)   (N x 128) @ (128 x 16) -> (N x 16)
__global__ __launch_bounds__(256) void linear_kernel(const float* __restrict__ x,
                                                     const float* __restrict__ W,
                                                     __half* __restrict__ h16, int N) {
    __shared__ float Ws[128 * 16];
    __shared__ float Xs[16 * 129];
    int tid = threadIdx.x;
    for (int i = tid; i < 2048; i += 256) Ws[i] = W[i];
    long long rbase = (long long)blockIdx.x * 16;
    for (int i = tid; i < 2048; i += 256) {
        int row = i >> 7, k = i & 127;
        long long grow = rbase + row;
        Xs[row * 129 + k] = (grow < N) ? x[grow * 128 + k] : 0.f;
    }
    __syncthreads();
    int rl = tid >> 4, c = tid & 15;
    float acc = 0.f;
#pragma unroll
    for (int k = 0; k < 128; ++k)
        acc = fmaf(Xs[rl * 129 + k], Ws[k * 16 + c], acc);
    long long row = rbase + rl;
    if (row < N) h16[row * 16 + c] = __float2half(acc);
}

// Pass 1: one col read builds the fine histogram (flushed to fcnt) AND
// reserves coarse space (regions pre-based at c*cap); second read places
// packed edges (r | (col&2047)<<17) into coarse regions.
__global__ __launch_bounds__(512) void pass1_kernel(const u32* __restrict__ ew,
                                                    const int* __restrict__ flag,
                                                    u32* __restrict__ fcnt,
                                                    u32* __restrict__ gcur1,
                                                    u32* __restrict__ binned1,
                                                    int E, int NB, int NB1) {
    __shared__ u32 fh[MAXNB];
    __shared__ u32 ccur[NB1_MAX];
    int t = threadIdx.x;
    for (int i = t; i < NB; i += 512) fh[i] = 0;
    __syncthreads();
    int i64 = *flag;
    const u64* ew64 = (const u64*)ew;
    int chunk = (E + (int)gridDim.x - 1) / (int)gridDim.x;
    int cb = blockIdx.x * chunk;
    int ce = min(cb + chunk, E);
    for (int e = cb + t; e < ce; e += 512) {
        u32 cl = i64 ? (u32)__builtin_nontemporal_load(&ew64[E + e])
                     : __builtin_nontemporal_load(&ew[E + e]);
        atomicAdd(&fh[cl >> CPB_LOG], 1u);
    }
    __syncthreads();
    for (int i = t; i < NB; i += 512)
        if (fh[i]) atomicAdd(&fcnt[i], fh[i]);
    if (t < NB1) {
        u32 n = 0;
        int base = t * SUBS, end = min(base + SUBS, NB);
        for (int k = base; k < end; ++k) n += fh[k];
        ccur[t] = n ? atomicAdd(&gcur1[t], n) : 0u;
    }
    __syncthreads();
    for (int e = cb + t; e < ce; e += 512) {
        u32 r, cl;
        if (i64) { r  = (u32)__builtin_nontemporal_load(&ew64[e]);
                   cl = (u32)__builtin_nontemporal_load(&ew64[E + e]); }
        else     { r  = __builtin_nontemporal_load(&ew[e]);
                   cl = __builtin_nontemporal_load(&ew[E + e]); }
        u32 c = cl >> C1_LOG;
        u32 pos = atomicAdd(&ccur[c], 1u);
        binned1[pos] = r | ((cl & ((1u << C1_LOG) - 1)) << 17);
    }
}

// Exclusive scan of NB fine counts -> fstart (immutable) + gcur2 (cursors).
__global__ __launch_bounds__(1024) void scan_kernel(const u32* __restrict__ fcnt,
                                                    u32* __restrict__ fstart,
                                                    u32* __restrict__ gcur2, int NB) {
    __shared__ u32 sm[1024];
    int t = threadIdx.x;
    u32 v0 = (2 * t < NB)     ? fcnt[2 * t]     : 0u;
    u32 v1 = (2 * t + 1 < NB) ? fcnt[2 * t + 1] : 0u;
    u32 v = v0 + v1;
    sm[t] = v;
    __syncthreads();
    for (int d = 1; d < 1024; d <<= 1) {
        u32 x = (t >= d) ? sm[t - d] : 0u;
        __syncthreads();
        sm[t] += x;
        __syncthreads();
    }
    u32 excl = sm[t] - v;
    if (2 * t < NB)     { fstart[2 * t] = excl;          gcur2[2 * t] = excl; }
    if (2 * t + 1 < NB) { fstart[2 * t + 1] = excl + v0; gcur2[2 * t + 1] = excl + v0; }
    if (t == 1023) fstart[NB] = sm[1023];
}

// Pass 2: per-region refinement (block b -> region b/RPB, slice b%RPB).
// Per-col 2048-counter LDS hist -> flushed to global cnt[N]; fine-bucket
// totals reduced from it for the gcur2 reservation; then place.
__global__ __launch_bounds__(512) void pass2_kernel(const u32* __restrict__ binned1,
                                                    const u32* __restrict__ gcur1,
                                                    u32* __restrict__ gcur2,
                                                    u32* __restrict__ binned2,
                                                    u32* __restrict__ cnt,
                                                    int cap, int N) {
    __shared__ u32 h2[1 << C1_LOG];   // 8 KB
    __shared__ u32 scur[SUBS];
    int b = blockIdx.x;
    int c = b / RPB, sub = b - c * RPB;
    int t = threadIdx.x;
    for (int i = t; i < (1 << C1_LOG); i += 512) h2[i] = 0;
    __syncthreads();
    int rbeg = c * cap;
    int rend = (int)gcur1[c];
    int len = rend - rbeg;
    int chunk = (len + RPB - 1) / RPB;
    int lo = rbeg + sub * chunk;
    int hi = min(lo + chunk, rend);
    for (int i = lo + t; i < hi; i += 512)
        atomicAdd(&h2[__builtin_nontemporal_load(&binned1[i]) >> 17], 1u);
    __syncthreads();
    int colbase = c << C1_LOG;
    for (int i = t; i < (1 << C1_LOG); i += 512) {
        u32 v = h2[i];
        if (v && colbase + i < N) atomicAdd(&cnt[colbase + i], v);
    }
    if (t < SUBS) {
        u32 n = 0;
#pragma unroll 8
        for (int k = 0; k < 64; ++k) n += h2[t * 64 + k];
        scur[t] = n ? atomicAdd(&gcur2[c * SUBS + t], n) : 0u;
    }
    __syncthreads();
    for (int i = lo + t; i < hi; i += 512) {
        u32 p = __builtin_nontemporal_load(&binned1[i]);
        u32 s = (p >> 17) >> CPB_LOG;
        u32 pos = atomicAdd(&scur[s], 1u);
        binned2[pos] = p & 0x7FFFFFu;          // r (17b) | col&63 (bits 17..22)
    }
}

// hs2[i] = half2( d*h[2i], d*h[2i+1] ), d = rsqrt(cnt[row]+1), row = i>>3.
__global__ __launch_bounds__(256) void hs_kernel(const __half2* __restrict__ h16,
                                                 const u32* __restrict__ cnt,
                                                 __half2* __restrict__ hs2, int M2) {
    int i = blockIdx.x * 256 + threadIdx.x;
    if (i >= M2) return;
    float d = rsqrtf((float)cnt[i >> 3] + 1.0f);
    float2 hv = __half22float2(h16[i]);
    hs2[i] = __floats2half2_rn(hv.x * d, hv.y * d);
}

// Fused sort+gather: one block per 64-col bucket. Scan cnt -> per-col offsets;
// place bucket entries into LDS tile in col order (1 LDS atomic/edge); then
// 32 work-stealing 16-lane groups gather + fused finalize. No global sorted.
__global__ __launch_bounds__(512) void fgather_kernel(const u32* __restrict__ binned2,
                                                      const u32* __restrict__ fstart,
                                                      const u32* __restrict__ cnt,
                                                      const __half2* __restrict__ hs2,
                                                      const float* __restrict__ bias,
                                                      float* __restrict__ out, int N) {
    __shared__ u32 tile[TCAP];
    __shared__ u32 cbeg[65];
    __shared__ u32 cur[64];
    __shared__ u32 colNext;
    int b = blockIdx.x, t = threadIdx.x;
    int cbase = b << CPB_LOG;
    u32 s = fstart[b], e = fstart[b + 1];
    int len = (int)(e - s);
    if (t < 64) {
        int col = cbase + t;
        u32 v = (col < N) ? cnt[col] : 0u;
        u32 inc = v;
#pragma unroll
        for (int off = 1; off < 64; off <<= 1) {
            u32 o = __shfl_up(inc, off, 64);
            if (t >= off) inc += o;
        }
        cbeg[t] = inc - v;
        cur[t] = inc - v;
        if (t == 63) cbeg[64] = inc;
    }
    if (t == 0) colNext = 0;
    __syncthreads();
    bool fits = (len <= TCAP);
    if (fits) {
        for (int i = t; i < len; i += 512) {
            u32 p = binned2[s + i];
            u32 pos = atomicAdd(&cur[(p >> 17) & 63u], 1u);
            tile[pos] = p & 0x1FFFFu;
        }
    }
    __syncthreads();

    int lane = t & 63;
    int l16 = t & 15;
    int c2 = l16 & 7, j = l16 >> 3;
    int leader = lane & 48;   // group-leader lane within the wave
    for (;;) {
        u32 mycol = 0;
        if (l16 == 0) mycol = atomicAdd(&colNext, 1u);
        mycol = __shfl(mycol, leader, 64);
        if (mycol >= 64u) break;
        int col = cbase + (int)mycol;
        if (col >= N) continue;
        u32 cs = cbeg[mycol], ce = cbeg[mycol + 1];
        float dt = rsqrtf((float)(ce - cs) + 1.0f);
        float ax = 0.f, ay = 0.f;
        if (fits) {
            u32 i = cs + j;
            for (; i + 6 < ce; i += 8) {
                u32 r0 = tile[i];
                u32 r1 = tile[i + 2];
                u32 r2 = tile[i + 4];
                u32 r3 = tile[i + 6];
                float2 v0 = __half22float2(hs2[(size_t)r0 * 8 + c2]);
                float2 v1 = __half22float2(hs2[(size_t)r1 * 8 + c2]);
                float2 v2 = __half22float2(hs2[(size_t)r2 * 8 + c2]);
                float2 v3 = __half22float2(hs2[(size_t)r3 * 8 + c2]);
                ax += (v0.x + v1.x) + (v2.x + v3.x);
                ay += (v0.y + v1.y) + (v2.y + v3.y);
            }
            for (; i < ce; i += 2) {
                u32 r = tile[i];
                float2 v = __half22float2(hs2[(size_t)r * 8 + c2]);
                ax += v.x; ay += v.y;
            }
        } else {
            // cold fallback: bucket overflowed LDS tile; filter-scan global
            for (int i = j; i < len; i += 2) {
                u32 p = binned2[s + i];
                if (((p >> 17) & 63u) == mycol) {
                    u32 r = p & 0x1FFFFu;
                    float2 v = __half22float2(hs2[(size_t)r * 8 + c2]);
                    ax += v.x; ay += v.y;
                }
            }
        }
        // j-slot reduce within the 16-lane group
        ax += __shfl_xor(ax, 8, 64);
        ay += __shfl_xor(ay, 8, 64);
        float2 sv = __half22float2(hs2[(size_t)col * 8 + c2]);
        float2 bb = ((const float2*)bias)[c2];
        float va = fmaxf(dt * (ax + sv.x) + bb.x, 0.f);
        float vb = fmaxf(dt * (ay + sv.y) + bb.y, 0.f);
        float m = fmaxf(va, vb);
#pragma unroll
        for (int off = 1; off < 8; off <<= 1) m = fmaxf(m, __shfl_xor(m, off, 64));
        float ss = expf(va - m) + expf(vb - m);
#pragma unroll
        for (int off = 1; off < 8; off <<= 1) ss += __shfl_xor(ss, off, 64);
        float ls = logf(ss);
        if (j == 0) {
            float2 o = { (va - m) - ls, (vb - m) - ls };
            ((float2*)(out + (size_t)col * 16))[c2] = o;
        }
    }
}

extern "C" void kernel_launch(void* const* d_in, const int* in_sizes, int n_in,
                              void* d_out, int out_size, void* d_ws, size_t ws_size,
                              hipStream_t stream) {
    const float* x  = (const float*)d_in[0];
    const u32*   ew = (const u32*)d_in[1];
    const float* W  = (const float*)d_in[2];
    const float* b  = (const float*)d_in[3];
    float* out = (float*)d_out;

    int N = in_sizes[0] / 128;   // 100000 (must be < 2^17 for packing)
    int E = in_sizes[1] / 2;     // 3200000
    int NB  = (N + 63) >> CPB_LOG;                   // 1563 fine buckets
    int NB1 = (N + ((1 << C1_LOG) - 1)) >> C1_LOG;   // 49 coarse regions
    int cap = E / NB1 + 8192;                        // slack region capacity

    char* wsb = (char*)d_ws;
    size_t off = 0;
    auto alloc = [&](size_t sz) { void* p = wsb + off; off = (off + sz + 15) & ~(size_t)15; return p; };
    int* flag     = (int*)alloc(4);
    u32* fcnt     = (u32*)alloc(MAXNB * 4);
    u32* fstart   = (u32*)alloc((MAXNB + 1) * 4);
    u32* gcur2    = (u32*)alloc(MAXNB * 4);
    u32* gcur1    = (u32*)alloc(NB1_MAX * 4);
    u32* cnt      = (u32*)alloc((size_t)N * 4);
    __half* h16   = (__half*)alloc((size_t)N * 32);
    __half2* hs2  = (__half2*)alloc((size_t)N * 32);
    u32* binned1  = (u32*)alloc((size_t)NB1 * cap * 4);
    u32* binned2  = (u32*)alloc((size_t)E * 4);

    hipMemsetAsync(fcnt, 0, MAXNB * 4, stream);
    hipMemsetAsync(cnt, 0, (size_t)N * 4, stream);
    init_kernel<<<1, 64, 0, stream>>>(ew, flag, gcur1, NB1, cap);
    linear_kernel<<<(N + 15) / 16, 256, 0, stream>>>(x, W, h16, N);
    pass1_kernel<<<GRID_BIN, 512, 0, stream>>>(ew, flag, fcnt, gcur1, binned1, E, NB, NB1);
    scan_kernel<<<1, 1024, 0, stream>>>(fcnt, fstart, gcur2, NB);
    pass2_kernel<<<NB1 * RPB, 512, 0, stream>>>(binned1, gcur1, gcur2, binned2, cnt, cap, N);
    hs_kernel<<<(N * 8 + 255) / 256, 256, 0, stream>>>((const __half2*)h16, cnt, hs2, N * 8);
    fgather_kernel<<<NB, 512, 0, stream>>>(binned2, fstart, cnt, hs2, b, out, N);
}

// Round 11
// 129.167 us; speedup vs baseline: 3.7980x; 1.0837x over previous
//
#include <hip/hip_runtime.h>
#include <hip/hip_fp16.h>

// ---------------------------------------------------------------------------
// GCNConv (PyG) + relu + log_softmax, MI355X.
// R10 lesson: linear was LDS-pipe-bound (2 ds_read per FMA, 43us vs 10us
// roofline); pass1's 49 coarse LDS cursors serialize (~10 lanes/counter).
// R11: (1) linear rewritten LDS-free — thread-per-row, acc[16] in VGPRs,
// W at wave-uniform addresses (scalar s_load path), x as per-lane float4
// streams; (2) pass1 wave-private hists + scatter cursors, 256x512 grid.
// ---------------------------------------------------------------------------

typedef unsigned int u32;
typedef unsigned long long u64;

#define MAXNB 2048
#define CPB_LOG 6          // fine bucket = 64 cols
#define C1_LOG 11          // coarse region = 2048 cols
#define SUBS 32            // fine buckets per coarse region
#define NB1_MAX 64
#define RPB 10             // pass2 blocks per coarse region
#define GRID_P1 256        // pass1 blocks (bigger chunks => bigger windows)
#define TCAP 3072          // fgather LDS tile capacity

// init: detect int64-vs-int32 edge storage + init coarse cursors to c*cap.
__global__ void init_kernel(const u32* __restrict__ ew, int* __restrict__ flag,
                            u32* __restrict__ gcur1, int NB1, int cap) {
    int t = threadIdx.x;
    if (t < NB1) gcur1[t] = (u32)(t * cap);
    if (t == 0) {
        int is64 = 1;
        for (int i = 0; i < 256; ++i) {
            if (ew[2 * i + 1] != 0u) { is64 = 0; break; }
        }
        *flag = is64;
    }
}

// h16 = fp16(x @ W). Thread-per-row, no LDS. W reads are wave-uniform ->
// scalar loads; x reads are per-lane sequential float4 streams.
__global__ __launch_bounds__(256) void linear_kernel(const float* __restrict__ x,
                                                     const float* __restrict__ W,
                                                     __half* __restrict__ h16, int N) {
    int gid = blockIdx.x * 256 + threadIdx.x;
    int nthreads = (int)gridDim.x * 256;
    const float4* x4 = (const float4*)x;
    const float4* W4 = (const float4*)W;   // W[k][c] row-major: row k = 4 float4s
    for (int row = gid; row < N; row += nthreads) {
        float acc[16];
#pragma unroll
        for (int c = 0; c < 16; ++c) acc[c] = 0.f;
        size_t xb = (size_t)row * 32;
#pragma unroll 2
        for (int chunk = 0; chunk < 32; ++chunk) {
            float4 xv = x4[xb + chunk];
            int k0 = chunk * 4;
            float xk[4] = { xv.x, xv.y, xv.z, xv.w };
#pragma unroll
            for (int q = 0; q < 4; ++q) {
                // wave-uniform addresses -> s_load into SGPRs
                float4 w0 = W4[(k0 + q) * 4 + 0];
                float4 w1 = W4[(k0 + q) * 4 + 1];
                float4 w2 = W4[(k0 + q) * 4 + 2];
                float4 w3 = W4[(k0 + q) * 4 + 3];
                float xv_q = xk[q];
                acc[0]  = fmaf(xv_q, w0.x, acc[0]);
                acc[1]  = fmaf(xv_q, w0.y, acc[1]);
                acc[2]  = fmaf(xv_q, w0.z, acc[2]);
                acc[3]  = fmaf(xv_q, w0.w, acc[3]);
                acc[4]  = fmaf(xv_q, w1.x, acc[4]);
                acc[5]  = fmaf(xv_q, w1.y, acc[5]);
                acc[6]  = fmaf(xv_q, w1.z, acc[6]);
                acc[7]  = fmaf(xv_q, w1.w, acc[7]);
                acc[8]  = fmaf(xv_q, w2.x, acc[8]);
                acc[9]  = fmaf(xv_q, w2.y, acc[9]);
                acc[10] = fmaf(xv_q, w2.z, acc[10]);
                acc[11] = fmaf(xv_q, w2.w, acc[11]);
                acc[12] = fmaf(xv_q, w3.x, acc[12]);
                acc[13] = fmaf(xv_q, w3.y, acc[13]);
                acc[14] = fmaf(xv_q, w3.z, acc[14]);
                acc[15] = fmaf(xv_q, w3.w, acc[15]);
            }
        }
        union { __half2 h2; u32 u; } pk[8];
#pragma unroll
        for (int p = 0; p < 8; ++p) pk[p].h2 = __floats2half2_rn(acc[2 * p], acc[2 * p + 1]);
        uint4* orow = (uint4*)(h16 + (size_t)row * 16);
        orow[0] = make_uint4(pk[0].u, pk[1].u, pk[2].u, pk[3].u);
        orow[1] = make_uint4(pk[4].u, pk[5].u, pk[6].u, pk[7].u);
    }
}

// Pass 1: phase A reads cols -> shared fine hist (fcnt flush) + WAVE-PRIVATE
// coarse hists; phase B derives per-wave scatter bases (1 global atomic per
// bucket per block); phase C scatters with wave-private cursors.
__global__ __launch_bounds__(512) void pass1_kernel(const u32* __restrict__ ew,
                                                    const int* __restrict__ flag,
                                                    u32* __restrict__ fcnt,
                                                    u32* __restrict__ gcur1,
                                                    u32* __restrict__ binned1,
                                                    int E, int NB, int NB1) {
    __shared__ u32 fh[MAXNB];          // shared fine hist (2048, low contention)
    __shared__ u32 cw[8 * NB1_MAX];    // wave-private coarse hist
    __shared__ u32 wb[8 * NB1_MAX];    // per-wave scatter cursors
    int t = threadIdx.x;
    int w = t >> 6;
    for (int i = t; i < NB; i += 512) fh[i] = 0;
    for (int i = t; i < 8 * NB1_MAX; i += 512) cw[i] = 0;
    __syncthreads();
    int i64 = *flag;
    const u64* ew64 = (const u64*)ew;
    int chunk = (E + (int)gridDim.x - 1) / (int)gridDim.x;
    int cb = blockIdx.x * chunk;
    int ce = min(cb + chunk, E);
    u32* cwm = &cw[w * NB1_MAX];
    for (int e = cb + t; e < ce; e += 512) {
        u32 cl = i64 ? (u32)__builtin_nontemporal_load(&ew64[E + e])
                     : __builtin_nontemporal_load(&ew[E + e]);
        atomicAdd(&fh[cl >> CPB_LOG], 1u);
        atomicAdd(&cwm[cl >> C1_LOG], 1u);
    }
    __syncthreads();
    for (int i = t; i < NB; i += 512)
        if (fh[i]) atomicAdd(&fcnt[i], fh[i]);
    if (t < NB1) {   // per-bucket: block total + per-wave exclusive bases
        u32 tot = 0;
        u32 pw[8];
#pragma unroll
        for (int q = 0; q < 8; ++q) { pw[q] = tot; tot += cw[q * NB1_MAX + t]; }
        u32 base = tot ? atomicAdd(&gcur1[t], tot) : 0u;
#pragma unroll
        for (int q = 0; q < 8; ++q) wb[q * NB1_MAX + t] = base + pw[q];
    }
    __syncthreads();
    u32* wbm = &wb[w * NB1_MAX];
    for (int e = cb + t; e < ce; e += 512) {
        u32 r, cl;
        if (i64) { r  = (u32)__builtin_nontemporal_load(&ew64[e]);
                   cl = (u32)__builtin_nontemporal_load(&ew64[E + e]); }
        else     { r  = __builtin_nontemporal_load(&ew[e]);
                   cl = __builtin_nontemporal_load(&ew[E + e]); }
        u32 c = cl >> C1_LOG;
        u32 pos = atomicAdd(&wbm[c], 1u);
        binned1[pos] = r | ((cl & ((1u << C1_LOG) - 1)) << 17);
    }
}

// Exclusive scan of NB fine counts -> fstart (immutable) + gcur2 (cursors).
__global__ __launch_bounds__(1024) void scan_kernel(const u32* __restrict__ fcnt,
                                                    u32* __restrict__ fstart,
                                                    u32* __restrict__ gcur2, int NB) {
    __shared__ u32 sm[1024];
    int t = threadIdx.x;
    u32 v0 = (2 * t < NB)     ? fcnt[2 * t]     : 0u;
    u32 v1 = (2 * t + 1 < NB) ? fcnt[2 * t + 1] : 0u;
    u32 v = v0 + v1;
    sm[t] = v;
    __syncthreads();
    for (int d = 1; d < 1024; d <<= 1) {
        u32 x = (t >= d) ? sm[t - d] : 0u;
        __syncthreads();
        sm[t] += x;
        __syncthreads();
    }
    u32 excl = sm[t] - v;
    if (2 * t < NB)     { fstart[2 * t] = excl;          gcur2[2 * t] = excl; }
    if (2 * t + 1 < NB) { fstart[2 * t + 1] = excl + v0; gcur2[2 * t + 1] = excl + v0; }
    if (t == 1023) fstart[NB] = sm[1023];
}

// Pass 2: per-region refinement (block b -> region b/RPB, slice b%RPB).
// Per-col 2048-counter LDS hist -> flushed to global cnt[N]; fine-bucket
// totals reduced from it for the gcur2 reservation; then place.
__global__ __launch_bounds__(512) void pass2_kernel(const u32* __restrict__ binned1,
                                                    const u32* __restrict__ gcur1,
                                                    u32* __restrict__ gcur2,
                                                    u32* __restrict__ binned2,
                                                    u32* __restrict__ cnt,
                                                    int cap, int N) {
    __shared__ u32 h2[1 << C1_LOG];   // 8 KB
    __shared__ u32 scur[SUBS];
    int b = blockIdx.x;
    int c = b / RPB, sub = b - c * RPB;
    int t = threadIdx.x;
    for (int i = t; i < (1 << C1_LOG); i += 512) h2[i] = 0;
    __syncthreads();
    int rbeg = c * cap;
    int rend = (int)gcur1[c];
    int len = rend - rbeg;
    int chunk = (len + RPB - 1) / RPB;
    int lo = rbeg + sub * chunk;
    int hi = min(lo + chunk, rend);
    for (int i = lo + t; i < hi; i += 512)
        atomicAdd(&h2[__builtin_nontemporal_load(&binned1[i]) >> 17], 1u);
    __syncthreads();
    int colbase = c << C1_LOG;
    for (int i = t; i < (1 << C1_LOG); i += 512) {
        u32 v = h2[i];
        if (v && colbase + i < N) atomicAdd(&cnt[colbase + i], v);
    }
    if (t < SUBS) {
        u32 n = 0;
#pragma unroll 8
        for (int k = 0; k < 64; ++k) n += h2[t * 64 + k];
        scur[t] = n ? atomicAdd(&gcur2[c * SUBS + t], n) : 0u;
    }
    __syncthreads();
    for (int i = lo + t; i < hi; i += 512) {
        u32 p = __builtin_nontemporal_load(&binned1[i]);
        u32 s = (p >> 17) >> CPB_LOG;
        u32 pos = atomicAdd(&scur[s], 1u);
        binned2[pos] = p & 0x7FFFFFu;          // r (17b) | col&63 (bits 17..22)
    }
}

// hs2[i] = half2( d*h[2i], d*h[2i+1] ), d = rsqrt(cnt[row]+1), row = i>>3.
__global__ __launch_bounds__(256) void hs_kernel(const __half2* __restrict__ h16,
                                                 const u32* __restrict__ cnt,
                                                 __half2* __restrict__ hs2, int M2) {
    int i = blockIdx.x * 256 + threadIdx.x;
    if (i >= M2) return;
    float d = rsqrtf((float)cnt[i >> 3] + 1.0f);
    float2 hv = __half22float2(h16[i]);
    hs2[i] = __floats2half2_rn(hv.x * d, hv.y * d);
}

// Fused sort+gather: one block per 64-col bucket. Scan cnt -> per-col offsets;
// place bucket entries into LDS tile in col order (1 LDS atomic/edge); then
// 32 work-stealing 16-lane groups gather + fused finalize.
__global__ __launch_bounds__(512) void fgather_kernel(const u32* __restrict__ binned2,
                                                      const u32* __restrict__ fstart,
                                                      const u32* __restrict__ cnt,
                                                      const __half2* __restrict__ hs2,
                                                      const float* __restrict__ bias,
                                                      float* __restrict__ out, int N) {
    __shared__ u32 tile[TCAP];
    __shared__ u32 cbeg[65];
    __shared__ u32 cur[64];
    __shared__ u32 colNext;
    int b = blockIdx.x, t = threadIdx.x;
    int cbase = b << CPB_LOG;
    u32 s = fstart[b], e = fstart[b + 1];
    int len = (int)(e - s);
    if (t < 64) {
        int col = cbase + t;
        u32 v = (col < N) ? cnt[col] : 0u;
        u32 inc = v;
#pragma unroll
        for (int off = 1; off < 64; off <<= 1) {
            u32 o = __shfl_up(inc, off, 64);
            if (t >= off) inc += o;
        }
        cbeg[t] = inc - v;
        cur[t] = inc - v;
        if (t == 63) cbeg[64] = inc;
    }
    if (t == 0) colNext = 0;
    __syncthreads();
    bool fits = (len <= TCAP);
    if (fits) {
        for (int i = t; i < len; i += 512) {
            u32 p = binned2[s + i];
            u32 pos = atomicAdd(&cur[(p >> 17) & 63u], 1u);
            tile[pos] = p & 0x1FFFFu;
        }
    }
    __syncthreads();

    int lane = t & 63;
    int l16 = t & 15;
    int c2 = l16 & 7, j = l16 >> 3;
    int leader = lane & 48;   // group-leader lane within the wave
    for (;;) {
        u32 mycol = 0;
        if (l16 == 0) mycol = atomicAdd(&colNext, 1u);
        mycol = __shfl(mycol, leader, 64);
        if (mycol >= 64u) break;
        int col = cbase + (int)mycol;
        if (col >= N) continue;
        u32 cs = cbeg[mycol], ce = cbeg[mycol + 1];
        float dt = rsqrtf((float)(ce - cs) + 1.0f);
        float ax = 0.f, ay = 0.f;
        if (fits) {
            u32 i = cs + j;
            for (; i + 6 < ce; i += 8) {
                u32 r0 = tile[i];
                u32 r1 = tile[i + 2];
                u32 r2 = tile[i + 4];
                u32 r3 = tile[i + 6];
                float2 v0 = __half22float2(hs2[(size_t)r0 * 8 + c2]);
                float2 v1 = __half22float2(hs2[(size_t)r1 * 8 + c2]);
                float2 v2 = __half22float2(hs2[(size_t)r2 * 8 + c2]);
                float2 v3 = __half22float2(hs2[(size_t)r3 * 8 + c2]);
                ax += (v0.x + v1.x) + (v2.x + v3.x);
                ay += (v0.y + v1.y) + (v2.y + v3.y);
            }
            for (; i < ce; i += 2) {
                u32 r = tile[i];
                float2 v = __half22float2(hs2[(size_t)r * 8 + c2]);
                ax += v.x; ay += v.y;
            }
        } else {
            for (int i = j; i < len; i += 2) {
                u32 p = binned2[s + i];
                if (((p >> 17) & 63u) == mycol) {
                    u32 r = p & 0x1FFFFu;
                    float2 v = __half22float2(hs2[(size_t)r * 8 + c2]);
                    ax += v.x; ay += v.y;
                }
            }
        }
        ax += __shfl_xor(ax, 8, 64);
        ay += __shfl_xor(ay, 8, 64);
        float2 sv = __half22float2(hs2[(size_t)col * 8 + c2]);
        float2 bb = ((const float2*)bias)[c2];
        float va = fmaxf(dt * (ax + sv.x) + bb.x, 0.f);
        float vb = fmaxf(dt * (ay + sv.y) + bb.y, 0.f);
        float m = fmaxf(va, vb);
#pragma unroll
        for (int off = 1; off < 8; off <<= 1) m = fmaxf(m, __shfl_xor(m, off, 64));
        float ss = expf(va - m) + expf(vb - m);
#pragma unroll
        for (int off = 1; off < 8; off <<= 1) ss += __shfl_xor(ss, off, 64);
        float ls = logf(ss);
        if (j == 0) {
            float2 o = { (va - m) - ls, (vb - m) - ls };
            ((float2*)(out + (size_t)col * 16))[c2] = o;
        }
    }
}

extern "C" void kernel_launch(void* const* d_in, const int* in_sizes, int n_in,
                              void* d_out, int out_size, void* d_ws, size_t ws_size,
                              hipStream_t stream) {
    const float* x  = (const float*)d_in[0];
    const u32*   ew = (const u32*)d_in[1];
    const float* W  = (const float*)d_in[2];
    const float* b  = (const float*)d_in[3];
    float* out = (float*)d_out;

    int N = in_sizes[0] / 128;   // 100000 (must be < 2^17 for packing)
    int E = in_sizes[1] / 2;     // 3200000
    int NB  = (N + 63) >> CPB_LOG;                   // 1563 fine buckets
    int NB1 = (N + ((1 << C1_LOG) - 1)) >> C1_LOG;   // 49 coarse regions
    int cap = E / NB1 + 8192;                        // slack region capacity

    char* wsb = (char*)d_ws;
    size_t off = 0;
    auto alloc = [&](size_t sz) { void* p = wsb + off; off = (off + sz + 15) & ~(size_t)15; return p; };
    int* flag     = (int*)alloc(4);
    u32* fcnt     = (u32*)alloc(MAXNB * 4);
    u32* fstart   = (u32*)alloc((MAXNB + 1) * 4);
    u32* gcur2    = (u32*)alloc(MAXNB * 4);
    u32* gcur1    = (u32*)alloc(NB1_MAX * 4);
    u32* cnt      = (u32*)alloc((size_t)N * 4);
    __half* h16   = (__half*)alloc((size_t)N * 32);
    __half2* hs2  = (__half2*)alloc((size_t)N * 32);
    u32* binned1  = (u32*)alloc((size_t)NB1 * cap * 4);
    u32* binned2  = (u32*)alloc((size_t)E * 4);

    hipMemsetAsync(fcnt, 0, MAXNB * 4, stream);
    hipMemsetAsync(cnt, 0, (size_t)N * 4, stream);
    init_kernel<<<1, 64, 0, stream>>>(ew, flag, gcur1, NB1, cap);
    linear_kernel<<<256, 256, 0, stream>>>(x, W, h16, N);
    pass1_kernel<<<GRID_P1, 512, 0, stream>>>(ew, flag, fcnt, gcur1, binned1, E, NB, NB1);
    scan_kernel<<<1, 1024, 0, stream>>>(fcnt, fstart, gcur2, NB);
    pass2_kernel<<<NB1 * RPB, 512, 0, stream>>>(binned1, gcur1, gcur2, binned2, cnt, cap, N);
    hs_kernel<<<(N * 8 + 255) / 256, 256, 0, stream>>>((const __half2*)h16, cnt, hs2, N * 8);
    fgather_kernel<<<NB, 512, 0, stream>>>(binned2, fstart, cnt, hs2, b, out, N);
}